// Round 1
// baseline (2575.641 us; speedup 1.0000x reference)
//
#include <hip/hip_runtime.h>
#include <math.h>

// ---------------------------------------------------------------------------
// VQ-VAE forward, fp32 baseline.
// Layouts: h, z, dinq, g all NHWC (channel contiguous).  Weights pre-transposed
// so the inner GEMM-ish loops read [k][o] with o contiguous (coalesced).
// ws layout (floats):
//   h/g   : 0          (16,777,216)   h = conv1 out, later reused for g
//   z     : 16777216   (4,194,304)
//   dinq  : 20971520   (4,194,304)
//   w2t   : 25165824   (262,144)   [r][s][c][o]
//   w1t   : 25427968   (262,144)   [pe][qe][t][u][c][o]
//   w2dt  : 25690112   (6,144)     [pe][qe][t][u][c][o3]
//   Et    : 25696256   (65,536)    [c][k]
//   s2    : 25761792   (512)       ||E_k||^2
//   idx   : 25762304   (32,768 int)
// total ~103.2 MB
// ---------------------------------------------------------------------------

// ---- conv1: x[32,3,128,128] -> relu -> h NHWC [32,64,64,128] ----
__global__ __launch_bounds__(256) void k_conv1(
    const float* __restrict__ x, const float* __restrict__ w1,
    const float* __restrict__ b1, float* __restrict__ h)
{
    int tid = blockIdx.x * 256 + threadIdx.x;
    int o = tid & 127;
    int q = (tid >> 7) & 63;
    int p = (tid >> 13) & 63;
    int n = tid >> 19;
    float acc = b1[o];
    #pragma unroll
    for (int c = 0; c < 3; ++c) {
        #pragma unroll
        for (int r = 0; r < 4; ++r) {
            int y = 2 * p + r - 1;
            if ((unsigned)y < 128u) {
                float4 w4 = *(const float4*)(w1 + (((o * 3 + c) * 4 + r) * 4));
                const float* xr = x + ((n * 3 + c) * 128 + y) * 128 + (2 * q - 1);
                float x0 = (q > 0)  ? xr[0] : 0.f;
                float x1 = xr[1];
                float x2 = xr[2];
                float x3 = (q < 63) ? xr[3] : 0.f;
                acc = fmaf(x0, w4.x, acc);
                acc = fmaf(x1, w4.y, acc);
                acc = fmaf(x2, w4.z, acc);
                acc = fmaf(x3, w4.w, acc);
            }
        }
    }
    h[tid] = acc > 0.f ? acc : 0.f;
}

// ---- weight transposes ----
__global__ void k_prep_w2t(const float* __restrict__ w2, float* __restrict__ w2t) {
    int tid = blockIdx.x * 256 + threadIdx.x;           // 262144
    int o = tid & 127, c = (tid >> 7) & 127, rs = tid >> 14;
    int r = rs >> 2, s = rs & 3;
    w2t[tid] = w2[((o * 128 + c) * 4 + r) * 4 + s];
}

__global__ void k_prep_w1t(const float* __restrict__ dw1, float* __restrict__ w1t) {
    int tid = blockIdx.x * 256 + threadIdx.x;           // 262144
    int o = tid & 127, c = (tid >> 7) & 127, m = tid >> 14; // m = pe*8+qe*4+t*2+u
    int pe = (m >> 3) & 1, qe = (m >> 2) & 1, t = (m >> 1) & 1, u = m & 1;
    w1t[tid] = dw1[((o * 128 + c) * 4 + (pe + 2 * t)) * 4 + (qe + 2 * u)];
}

__global__ void k_prep_w2dt(const float* __restrict__ dw2, float* __restrict__ w2dt) {
    int tid = blockIdx.x * 256 + threadIdx.x;           // 6144
    if (tid >= 6144) return;
    int o = tid % 3; int rest = tid / 3; int c = rest & 127; int m = rest >> 7;
    int pe = (m >> 3) & 1, qe = (m >> 2) & 1, t = (m >> 1) & 1, u = m & 1;
    w2dt[tid] = dw2[((o * 128 + c) * 4 + (pe + 2 * t)) * 4 + (qe + 2 * u)];
}

__global__ void k_prep_Et(const float* __restrict__ E, float* __restrict__ Et) {
    int tid = blockIdx.x * 256 + threadIdx.x;           // 65536
    int k = tid & 511, c = tid >> 9;
    Et[tid] = E[k * 128 + c];
}

__global__ void k_prep_sumE2(const float* __restrict__ E, float* __restrict__ s2) {
    int k = blockIdx.x * 256 + threadIdx.x;             // 512
    float a = 0.f;
    const float* e = E + k * 128;
    for (int c = 0; c < 128; ++c) a = fmaf(e[c], e[c], a);
    s2[k] = a;
}

#define GSTEP(HV, WPTR) { \
    float4 wa = *(const float4*)(WPTR); \
    float4 wb = *(const float4*)((WPTR) + 4); \
    acc[0] = fmaf((HV), wa.x, acc[0]); acc[1] = fmaf((HV), wa.y, acc[1]); \
    acc[2] = fmaf((HV), wa.z, acc[2]); acc[3] = fmaf((HV), wa.w, acc[3]); \
    acc[4] = fmaf((HV), wb.x, acc[4]); acc[5] = fmaf((HV), wb.y, acc[5]); \
    acc[6] = fmaf((HV), wb.z, acc[6]); acc[7] = fmaf((HV), wb.w, acc[7]); }

// ---- conv2: h NHWC -> z NHWC [32,32,32,128], bias, no relu ----
__global__ __launch_bounds__(256) void k_conv2(
    const float* __restrict__ h, const float* __restrict__ w2t,
    const float* __restrict__ b2, float* __restrict__ z)
{
    __shared__ float hl[16][132];
    int posbase = blockIdx.x * 16;          // (n*32+p)*32+q, 2048 blocks
    int n = posbase >> 10;
    int p = (posbase >> 5) & 31;
    int q0 = posbase & 31;                  // 0 or 16
    int t = threadIdx.x;
    int pl = t >> 4;                        // local position 0..15
    int ot = t & 15;                        // o-group: o = ot*8..ot*8+7
    float acc[8];
    #pragma unroll
    for (int j = 0; j < 8; ++j) acc[j] = 0.f;

    for (int rs = 0; rs < 16; ++rs) {
        int r = rs >> 2, s = rs & 3;
        int y = 2 * p + r - 1;
        __syncthreads();
        {   // stage 16 rows x 128 c
            int flat = t * 8;
            int qq = flat >> 7;             // == t>>4
            int c0 = flat & 127;
            int xx = 2 * (q0 + qq) + s - 1;
            float4 v0 = {0.f, 0.f, 0.f, 0.f}, v1 = {0.f, 0.f, 0.f, 0.f};
            if (((unsigned)y < 64u) && ((unsigned)xx < 64u)) {
                const float* src = h + (((n * 64 + y) * 64 + xx) * 128 + c0);
                v0 = *(const float4*)src;
                v1 = *(const float4*)(src + 4);
            }
            *(float4*)&hl[qq][c0] = v0;
            *(float4*)&hl[qq][c0 + 4] = v1;
        }
        __syncthreads();
        const float* wbase = w2t + rs * 16384 + ot * 8;
        for (int c = 0; c < 128; c += 4) {
            float4 hv = *(const float4*)&hl[pl][c];
            GSTEP(hv.x, wbase + (c + 0) * 128);
            GSTEP(hv.y, wbase + (c + 1) * 128);
            GSTEP(hv.z, wbase + (c + 2) * 128);
            GSTEP(hv.w, wbase + (c + 3) * 128);
        }
    }
    int q = q0 + pl;
    float* dst = z + (((n * 32 + p) * 32 + q) * 128 + ot * 8);
    const float* bb = b2 + ot * 8;
    #pragma unroll
    for (int j = 0; j < 8; ++j) dst[j] = acc[j] + bb[j];
}

// ---- VQ: argmin_k ( ||E_k||^2 - 2 z.E_k ) per row of z ----
__global__ __launch_bounds__(256) void k_vq(
    const float* __restrict__ z, const float* __restrict__ Et,
    const float* __restrict__ s2, int* __restrict__ idxout)
{
    __shared__ float zl[16][132];
    int rowbase = blockIdx.x * 16;          // 2048 blocks
    int t = threadIdx.x;
    int pl = t >> 4, ot = t & 15;
    {
        int flat = t * 8;
        int rr = flat >> 7;
        int c0 = flat & 127;
        const float* src = z + (rowbase + rr) * 128 + c0;
        float4 v0 = *(const float4*)src;
        float4 v1 = *(const float4*)(src + 4);
        *(float4*)&zl[rr][c0] = v0;
        *(float4*)&zl[rr][c0 + 4] = v1;
    }
    __syncthreads();
    float bestv = INFINITY;
    int besti = 0;
    for (int pass = 0; pass < 4; ++pass) {
        int k0 = pass * 128 + ot * 8;
        float acc[8];
        #pragma unroll
        for (int j = 0; j < 8; ++j) acc[j] = 0.f;
        for (int c = 0; c < 128; c += 4) {
            float4 zv = *(const float4*)&zl[pl][c];
            GSTEP(zv.x, Et + (c + 0) * 512 + k0);
            GSTEP(zv.y, Et + (c + 1) * 512 + k0);
            GSTEP(zv.z, Et + (c + 2) * 512 + k0);
            GSTEP(zv.w, Et + (c + 3) * 512 + k0);
        }
        #pragma unroll
        for (int j = 0; j < 8; ++j) {
            float score = s2[k0 + j] - 2.f * acc[j];
            if (score < bestv) { bestv = score; besti = k0 + j; }
        }
    }
    #pragma unroll
    for (int m = 8; m >= 1; m >>= 1) {
        float ov = __shfl_xor(bestv, m, 16);
        int   oi = __shfl_xor(besti, m, 16);
        if (ov < bestv || (ov == bestv && oi < besti)) { bestv = ov; besti = oi; }
    }
    if (ot == 0) idxout[rowbase + pl] = besti;
}

// ---- scatter: dinq NHWC [32,32,32,128] <- E[idx] through the no-permute reshape ----
__global__ void k_scatter(const float* __restrict__ E, const int* __restrict__ idx,
                          float* __restrict__ dinq)
{
    int tid = blockIdx.x * 256 + threadIdx.x;   // 4,194,304
    int c  = tid & 127;
    int xx = (tid >> 7) & 31;
    int y  = (tid >> 12) & 31;
    int n  = tid >> 17;
    int pos = (y << 5) | xx;
    int row = (n << 10) + (c << 3) + (pos >> 7);
    int col = pos & 127;
    dinq[tid] = E[idx[row] * 128 + col];
}

// ---- deconv1: dinq NHWC -> relu -> g NHWC [32,64,64,128] ----
__global__ __launch_bounds__(256) void k_deconv1(
    const float* __restrict__ dinq, const float* __restrict__ w1t,
    const float* __restrict__ b1, float* __restrict__ g)
{
    __shared__ float dl[16][132];
    int bid = blockIdx.x;                   // 8192 = n(32) pe(2) qe(2) a(32) bt(2)
    int bt = bid & 1;
    int a  = (bid >> 1) & 31;
    int qe = (bid >> 6) & 1;
    int pe = (bid >> 7) & 1;
    int n  = bid >> 8;
    int t = threadIdx.x;
    int pl = t >> 4, ot = t & 15;
    int b0 = bt * 16;
    float acc[8];
    #pragma unroll
    for (int j = 0; j < 8; ++j) acc[j] = 0.f;

    for (int tu = 0; tu < 4; ++tu) {
        int tt = tu >> 1, u = tu & 1;
        int iy = a + pe + tt - 1;
        __syncthreads();
        {
            int flat = t * 8;
            int bl = flat >> 7;
            int c0 = flat & 127;
            int ix = b0 + bl + qe + u - 1;
            float4 v0 = {0.f, 0.f, 0.f, 0.f}, v1 = {0.f, 0.f, 0.f, 0.f};
            if (((unsigned)iy < 32u) && ((unsigned)ix < 32u)) {
                const float* src = dinq + (((n * 32 + iy) * 32 + ix) * 128 + c0);
                v0 = *(const float4*)src;
                v1 = *(const float4*)(src + 4);
            }
            *(float4*)&dl[bl][c0] = v0;
            *(float4*)&dl[bl][c0 + 4] = v1;
        }
        __syncthreads();
        const float* wbase = w1t + ((((pe * 2 + qe) * 2 + tt) * 2 + u) * 128) * 128 + ot * 8;
        for (int c = 0; c < 128; c += 4) {
            float4 dv = *(const float4*)&dl[pl][c];
            GSTEP(dv.x, wbase + (c + 0) * 128);
            GSTEP(dv.y, wbase + (c + 1) * 128);
            GSTEP(dv.z, wbase + (c + 2) * 128);
            GSTEP(dv.w, wbase + (c + 3) * 128);
        }
    }
    int b = b0 + pl;
    int y = 2 * a + pe, x = 2 * b + qe;
    float* dst = g + (((n * 64 + y) * 64 + x) * 128 + ot * 8);
    const float* bb = b1 + ot * 8;
    #pragma unroll
    for (int j = 0; j < 8; ++j) {
        float v = acc[j] + bb[j];
        dst[j] = v > 0.f ? v : 0.f;
    }
}

// ---- deconv2 + sigmoid: g NHWC -> out NCHW [32,3,128,128] ----
__global__ __launch_bounds__(128) void k_deconv2(
    const float* __restrict__ g, const float* __restrict__ w2dt,
    const float* __restrict__ b2, float* __restrict__ out)
{
    __shared__ float wl[2][2][2][128][4];   // [qe][t][u][c][o]
    int bid = blockIdx.x;                   // 4096 = n(32) * y(128)
    int y = bid & 127, n = bid >> 7;
    int pe = y & 1, a = y >> 1;
    int t = threadIdx.x;
    int qe = t >> 6, b = t & 63;

    for (int i = t; i < 3072; i += 128) {
        int o = i % 3; int rest = i / 3; int c = rest & 127; int m8 = rest >> 7;
        wl[m8 >> 2][(m8 >> 1) & 1][m8 & 1][c][o] =
            w2dt[((pe * 8 + m8) * 128 + c) * 3 + o];
    }
    __syncthreads();

    float a0 = 0.f, a1 = 0.f, a2 = 0.f;
    for (int tu = 0; tu < 4; ++tu) {
        int tt = tu >> 1, u = tu & 1;
        int iy = a + pe + tt - 1;
        int ix = b + qe + u - 1;
        if (((unsigned)iy < 64u) && ((unsigned)ix < 64u)) {
            const float* gr = g + ((n * 64 + iy) * 64 + ix) * 128;
            const float* wc = &wl[qe][tt][u][0][0];
            for (int c = 0; c < 128; c += 4) {
                float4 gv = *(const float4*)(gr + c);
                const float* w0 = wc + c * 4;
                a0 = fmaf(gv.x, w0[0],  a0); a1 = fmaf(gv.x, w0[1],  a1); a2 = fmaf(gv.x, w0[2],  a2);
                a0 = fmaf(gv.y, w0[4],  a0); a1 = fmaf(gv.y, w0[5],  a1); a2 = fmaf(gv.y, w0[6],  a2);
                a0 = fmaf(gv.z, w0[8],  a0); a1 = fmaf(gv.z, w0[9],  a1); a2 = fmaf(gv.z, w0[10], a2);
                a0 = fmaf(gv.w, w0[12], a0); a1 = fmaf(gv.w, w0[13], a1); a2 = fmaf(gv.w, w0[14], a2);
            }
        }
    }
    int x = 2 * b + qe;
    float v0 = 1.f / (1.f + expf(-(a0 + b2[0])));
    float v1 = 1.f / (1.f + expf(-(a1 + b2[1])));
    float v2 = 1.f / (1.f + expf(-(a2 + b2[2])));
    out[((n * 3 + 0) * 128 + y) * 128 + x] = v0;
    out[((n * 3 + 1) * 128 + y) * 128 + x] = v1;
    out[((n * 3 + 2) * 128 + y) * 128 + x] = v2;
}

extern "C" void kernel_launch(void* const* d_in, const int* in_sizes, int n_in,
                              void* d_out, int out_size, void* d_ws, size_t ws_size,
                              hipStream_t stream) {
    const float* x   = (const float*)d_in[0];
    const float* ew1 = (const float*)d_in[1];
    const float* eb1 = (const float*)d_in[2];
    const float* ew2 = (const float*)d_in[3];
    const float* eb2 = (const float*)d_in[4];
    const float* E   = (const float*)d_in[5];
    const float* dw1 = (const float*)d_in[6];
    const float* db1 = (const float*)d_in[7];
    const float* dw2 = (const float*)d_in[8];
    const float* db2 = (const float*)d_in[9];
    float* out = (float*)d_out;

    float* ws   = (float*)d_ws;
    float* h    = ws;                   // conv1 out, reused as g after conv2
    float* z    = ws + 16777216;
    float* dinq = ws + 20971520;
    float* w2t  = ws + 25165824;
    float* w1t  = ws + 25427968;
    float* w2dt = ws + 25690112;
    float* Et   = ws + 25696256;
    float* s2   = ws + 25761792;
    int*   idx  = (int*)(ws + 25762304);

    k_prep_w2t  <<<1024, 256, 0, stream>>>(ew2, w2t);
    k_prep_w1t  <<<1024, 256, 0, stream>>>(dw1, w1t);
    k_prep_w2dt <<<24,   256, 0, stream>>>(dw2, w2dt);
    k_prep_Et   <<<256,  256, 0, stream>>>(E, Et);
    k_prep_sumE2<<<2,    256, 0, stream>>>(E, s2);

    k_conv1  <<<65536, 256, 0, stream>>>(x, ew1, eb1, h);
    k_conv2  <<<2048,  256, 0, stream>>>(h, w2t, eb2, z);
    k_vq     <<<2048,  256, 0, stream>>>(z, Et, s2, idx);
    k_scatter<<<16384, 256, 0, stream>>>(E, idx, dinq);
    k_deconv1<<<8192,  256, 0, stream>>>(dinq, w1t, db1, h /* = g */);
    k_deconv2<<<4096,  128, 0, stream>>>(h /* = g */, w2dt, db2, out);
}

// Round 2
// 557.849 us; speedup vs baseline: 4.6171x; 4.6171x over previous
//
#include <hip/hip_runtime.h>
#include <hip/hip_bf16.h>
#include <math.h>

// ---------------------------------------------------------------------------
// VQ-VAE forward. conv2 / deconv1 / vq are bf16 MFMA implicit GEMMs
// (128x128 tile, K-step 128, global_load_lds staging, XOR-swizzled LDS).
// ws layout (bytes):
//   0          : hb   bf16 [32][66][66][128] (padded conv1 out)  35,684,352
//                g    f32  [32][64][64][128] (deconv1 out, UNION w/ hb)
//   67108864   : zb   bf16 [32768][128]                           8,388,608
//   75497472   : dq   bf16 [32][34][34][128] (padded scatter out) 9,469,952
//   84967424   : w2s  bf16 [16 rs][128 o][128 c] pre-swizzled       524,288
//   85491712   : w1s  bf16 [16 m ][128 o][128 c] pre-swizzled       524,288
//   86016000   : Eb   bf16 [512 k][128 c]  pre-swizzled             131,072
//   86147072   : w2d  f32  [6144]                                    24,576
//   86171648   : s2   f32  [512]                                      2,048
//   86173696   : idx  int  [32768]                                  131,072
// total ~86.3 MB
// ---------------------------------------------------------------------------

typedef __attribute__((ext_vector_type(8))) short bf16x8;
typedef __attribute__((ext_vector_type(4))) float f32x4;

__device__ __forceinline__ void gload16(const void* g, const void* l) {
    __builtin_amdgcn_global_load_lds(
        (const __attribute__((address_space(1))) void*)g,
        (__attribute__((address_space(3))) void*)l, 16, 0, 0);
}

// byte offset of the 16B fragment (row, k-sub ks) in a swizzled 128x128 bf16 tile
__device__ __forceinline__ int fragoff(int row, int ks, int lane) {
    return (row << 8) + (((ks << 6) + (lane & 0x30)) ^ ((row & 7) << 4));
}

// ---- conv1: x[32,3,128,128] fp32 -> relu -> hb bf16 padded [32,66,66,128] ----
__global__ __launch_bounds__(256) void k_conv1(
    const float* __restrict__ x, const float* __restrict__ w1,
    const float* __restrict__ b1, __hip_bfloat16* __restrict__ hb)
{
    int tid = blockIdx.x * 256 + threadIdx.x;   // 32*66*66*128 = 17,842,176
    int o = tid & 127;
    int rest = tid >> 7;
    int xx = rest % 66;
    int t2 = rest / 66;
    int yy = t2 % 66;
    int n = t2 / 66;
    float acc = 0.f;
    if (yy >= 1 && yy <= 64 && xx >= 1 && xx <= 64) {
        int p = yy - 1, q = xx - 1;
        acc = b1[o];
        #pragma unroll
        for (int c = 0; c < 3; ++c) {
            #pragma unroll
            for (int r = 0; r < 4; ++r) {
                int y = 2 * p + r - 1;
                if ((unsigned)y < 128u) {
                    float4 w4 = *(const float4*)(w1 + (((o * 3 + c) * 4 + r) * 4));
                    const float* xr = x + ((n * 3 + c) * 128 + y) * 128 + (2 * q - 1);
                    float x0 = (q > 0)  ? xr[0] : 0.f;
                    float x1 = xr[1];
                    float x2 = xr[2];
                    float x3 = (q < 63) ? xr[3] : 0.f;
                    acc = fmaf(x0, w4.x, acc);
                    acc = fmaf(x1, w4.y, acc);
                    acc = fmaf(x2, w4.z, acc);
                    acc = fmaf(x3, w4.w, acc);
                }
            }
        }
        acc = acc > 0.f ? acc : 0.f;
    }
    hb[tid] = __float2bfloat16(acc);
}

// ---- weight/codebook prep (pre-swizzled bf16 layouts) ----
__global__ void k_prep_w2s(const float* __restrict__ ew2, __hip_bfloat16* __restrict__ w2s) {
    int tid = blockIdx.x * 256 + threadIdx.x;   // 262144
    int cpos = tid & 127, o = (tid >> 7) & 127, rs = tid >> 14;
    int r = rs >> 2, s = rs & 3;
    int slot = cpos >> 3, e = cpos & 7;
    int csrc = ((slot ^ (o & 7)) << 3) | e;
    w2s[tid] = __float2bfloat16(ew2[((o * 128 + csrc) * 4 + r) * 4 + s]);
}

__global__ void k_prep_w1s(const float* __restrict__ dw1, __hip_bfloat16* __restrict__ w1s) {
    int tid = blockIdx.x * 256 + threadIdx.x;   // 262144
    int cpos = tid & 127, o = (tid >> 7) & 127, m = tid >> 14;
    int pe = (m >> 3) & 1, qe = (m >> 2) & 1, tt = (m >> 1) & 1, u = m & 1;
    int slot = cpos >> 3, e = cpos & 7;
    int csrc = ((slot ^ (o & 7)) << 3) | e;
    w1s[tid] = __float2bfloat16(dw1[((o * 128 + csrc) * 4 + (pe + 2 * tt)) * 4 + (qe + 2 * u)]);
}

__global__ void k_prep_Eb(const float* __restrict__ E, __hip_bfloat16* __restrict__ Eb) {
    int tid = blockIdx.x * 256 + threadIdx.x;   // 65536
    int cpos = tid & 127, k = tid >> 7;
    int slot = cpos >> 3, e = cpos & 7;
    int csrc = ((slot ^ (k & 7)) << 3) | e;
    Eb[tid] = __float2bfloat16(E[k * 128 + csrc]);
}

__global__ void k_prep_w2dt(const float* __restrict__ dw2, float* __restrict__ w2dt) {
    int tid = blockIdx.x * 256 + threadIdx.x;   // 6144
    if (tid >= 6144) return;
    int o = tid % 3; int rest = tid / 3; int c = rest & 127; int m = rest >> 7;
    int pe = (m >> 3) & 1, qe = (m >> 2) & 1, t = (m >> 1) & 1, u = m & 1;
    w2dt[tid] = dw2[((o * 128 + c) * 4 + (pe + 2 * t)) * 4 + (qe + 2 * u)];
}

__global__ void k_prep_sumE2(const float* __restrict__ E, float* __restrict__ s2) {
    int k = blockIdx.x * 256 + threadIdx.x;     // 512
    float a = 0.f;
    const float* e = E + k * 128;
    for (int c = 0; c < 128; ++c) a = fmaf(e[c], e[c], a);
    s2[k] = a;
}

// ---- conv2: hb (padded bf16) -> zb bf16 [32768][128] ----
__global__ __launch_bounds__(256) void k_conv2(
    const __hip_bfloat16* __restrict__ hb, const __hip_bfloat16* __restrict__ w2s,
    const float* __restrict__ b2, __hip_bfloat16* __restrict__ zb)
{
    __shared__ char smem[65536];
    int t = threadIdx.x, lane = t & 63, w = t >> 6;
    int wr = w >> 1, wc = w & 1;
    int posbase = blockIdx.x << 7;              // 256 blocks
    int n = posbase >> 10, prow0 = (posbase >> 5) & 31;

    int aoff[8];
    #pragma unroll
    for (int i = 0; i < 8; ++i) {
        int row = (((w << 3) + i) << 2) + (lane >> 4);
        int slot = lane & 15;
        int p = prow0 + (row >> 5), q = row & 31;
        int csw = (slot ^ (row & 7)) << 3;
        aoff[i] = (((n * 66 + 2 * p) * 66 + 2 * q) << 7) + csw;
    }

    f32x4 acc[4][4];
    #pragma unroll
    for (int mi = 0; mi < 4; ++mi)
        #pragma unroll
        for (int ni = 0; ni < 4; ++ni) acc[mi][ni] = (f32x4){0.f, 0.f, 0.f, 0.f};

    for (int rs = 0; rs < 16; ++rs) {
        __syncthreads();
        int rsoff = (((rs >> 2) * 66 + (rs & 3)) << 7);
        const __hip_bfloat16* wsl = w2s + (rs << 14);
        #pragma unroll
        for (int i = 0; i < 8; ++i) {
            gload16(hb + aoff[i] + rsoff, &smem[((w << 3) + i) << 10]);
            gload16(wsl + ((((w << 3) + i) << 9) + (lane << 3)), &smem[32768 + (((w << 3) + i) << 10)]);
        }
        __syncthreads();
        #pragma unroll
        for (int ks = 0; ks < 4; ++ks) {
            bf16x8 av[4], bv[4];
            #pragma unroll
            for (int mi = 0; mi < 4; ++mi)
                av[mi] = *(const bf16x8*)&smem[fragoff((wr << 6) + (mi << 4) + (lane & 15), ks, lane)];
            #pragma unroll
            for (int ni = 0; ni < 4; ++ni)
                bv[ni] = *(const bf16x8*)&smem[32768 + fragoff((wc << 6) + (ni << 4) + (lane & 15), ks, lane)];
            #pragma unroll
            for (int mi = 0; mi < 4; ++mi)
                #pragma unroll
                for (int ni = 0; ni < 4; ++ni)
                    acc[mi][ni] = __builtin_amdgcn_mfma_f32_16x16x32_bf16(av[mi], bv[ni], acc[mi][ni], 0, 0, 0);
        }
    }

    int rg = (lane >> 4) << 2;
    #pragma unroll
    for (int mi = 0; mi < 4; ++mi)
        #pragma unroll
        for (int ni = 0; ni < 4; ++ni) {
            int o = (wc << 6) + (ni << 4) + (lane & 15);
            float bias = b2[o];
            #pragma unroll
            for (int j = 0; j < 4; ++j) {
                int pos = posbase + (wr << 6) + (mi << 4) + rg + j;
                zb[(pos << 7) + o] = __float2bfloat16(acc[mi][ni][j] + bias);
            }
        }
}

// ---- vq: zb bf16 x Eb bf16 MFMA, fused argmin -> idx ----
__global__ __launch_bounds__(256) void k_vq(
    const __hip_bfloat16* __restrict__ zb, const __hip_bfloat16* __restrict__ Eb,
    const float* __restrict__ s2, int* __restrict__ idxout)
{
    __shared__ char smem[65536];
    int t = threadIdx.x, lane = t & 63, w = t >> 6;
    int wr = w >> 1, wc = w & 1;
    int posbase = blockIdx.x << 7;              // 256 blocks

    // stage A (z tile) once
    #pragma unroll
    for (int i = 0; i < 8; ++i) {
        int row = (((w << 3) + i) << 2) + (lane >> 4);
        int slot = lane & 15;
        int csw = (slot ^ (row & 7)) << 3;
        gload16(zb + (((posbase + row) << 7) + csw), &smem[((w << 3) + i) << 10]);
    }

    float bvv[4][4];
    int   bii[4][4];
    #pragma unroll
    for (int mi = 0; mi < 4; ++mi)
        #pragma unroll
        for (int j = 0; j < 4; ++j) { bvv[mi][j] = 3.4e38f; bii[mi][j] = 0; }

    for (int n0 = 0; n0 < 4; ++n0) {
        __syncthreads();
        const __hip_bfloat16* esl = Eb + (n0 << 14);
        #pragma unroll
        for (int i = 0; i < 8; ++i)
            gload16(esl + ((((w << 3) + i) << 9) + (lane << 3)), &smem[32768 + (((w << 3) + i) << 10)]);
        __syncthreads();

        f32x4 acc[4][4];
        #pragma unroll
        for (int mi = 0; mi < 4; ++mi)
            #pragma unroll
            for (int ni = 0; ni < 4; ++ni) acc[mi][ni] = (f32x4){0.f, 0.f, 0.f, 0.f};

        #pragma unroll
        for (int ks = 0; ks < 4; ++ks) {
            bf16x8 av[4], bv[4];
            #pragma unroll
            for (int mi = 0; mi < 4; ++mi)
                av[mi] = *(const bf16x8*)&smem[fragoff((wr << 6) + (mi << 4) + (lane & 15), ks, lane)];
            #pragma unroll
            for (int ni = 0; ni < 4; ++ni)
                bv[ni] = *(const bf16x8*)&smem[32768 + fragoff((wc << 6) + (ni << 4) + (lane & 15), ks, lane)];
            #pragma unroll
            for (int mi = 0; mi < 4; ++mi)
                #pragma unroll
                for (int ni = 0; ni < 4; ++ni)
                    acc[mi][ni] = __builtin_amdgcn_mfma_f32_16x16x32_bf16(av[mi], bv[ni], acc[mi][ni], 0, 0, 0);
        }

        float s2v[4];
        #pragma unroll
        for (int ni = 0; ni < 4; ++ni)
            s2v[ni] = s2[(n0 << 7) + (wc << 6) + (ni << 4) + (lane & 15)];
        #pragma unroll
        for (int mi = 0; mi < 4; ++mi)
            #pragma unroll
            for (int ni = 0; ni < 4; ++ni) {
                int k = (n0 << 7) + (wc << 6) + (ni << 4) + (lane & 15);
                #pragma unroll
                for (int j = 0; j < 4; ++j) {
                    float sc = s2v[ni] - 2.f * acc[mi][ni][j];
                    if (sc < bvv[mi][j]) { bvv[mi][j] = sc; bii[mi][j] = k; }
                }
            }
    }

    __syncthreads();   // everyone done reading A/B; reuse A region for reduction
    float* redv = (float*)smem;
    int*   redi = (int*)(smem + 1024);
    #pragma unroll
    for (int mi = 0; mi < 4; ++mi)
        #pragma unroll
        for (int j = 0; j < 4; ++j) {
            float v = bvv[mi][j];
            int   ix = bii[mi][j];
            #pragma unroll
            for (int m = 1; m < 16; m <<= 1) {
                float ov = __shfl_xor(v, m, 64);
                int   oi = __shfl_xor(ix, m, 64);
                if (ov < v || (ov == v && oi < ix)) { v = ov; ix = oi; }
            }
            if ((lane & 15) == 0) {
                int row = (wr << 6) + (mi << 4) + ((lane >> 4) << 2) + j;
                redv[row * 2 + wc] = v;
                redi[row * 2 + wc] = ix;
            }
        }
    __syncthreads();
    if (t < 128) {
        float v0 = redv[t * 2], v1 = redv[t * 2 + 1];
        int   i0 = redi[t * 2], i1 = redi[t * 2 + 1];
        int best = (v1 < v0 || (v1 == v0 && i1 < i0)) ? i1 : i0;
        idxout[posbase + t] = best;
    }
}

// ---- scatter: dq bf16 padded [32,34,34,128] <- E[idx] (no-permute reshape) ----
__global__ void k_scatter(const float* __restrict__ E, const int* __restrict__ idx,
                          __hip_bfloat16* __restrict__ dq)
{
    int tid = blockIdx.x * 256 + threadIdx.x;   // 32*34*34*128 = 4,734,976
    int c = tid & 127;
    int rest = tid >> 7;
    int xx = rest % 34;
    int t2 = rest / 34;
    int yy = t2 % 34;
    int n = t2 / 34;
    float v = 0.f;
    if (yy >= 1 && yy <= 32 && xx >= 1 && xx <= 32) {
        int y = yy - 1, x = xx - 1;
        int pos = (y << 5) | x;
        int row = (n << 10) + (c << 3) + (pos >> 7);
        int col = pos & 127;
        v = E[idx[row] * 128 + col];
    }
    dq[tid] = __float2bfloat16(v);
}

// ---- deconv1: dq (padded bf16) -> relu -> g f32 NHWC [32,64,64,128] ----
__global__ __launch_bounds__(256) void k_deconv1(
    const __hip_bfloat16* __restrict__ dq, const __hip_bfloat16* __restrict__ w1s,
    const float* __restrict__ b1, float* __restrict__ g)
{
    __shared__ char smem[65536];
    int t = threadIdx.x, lane = t & 63, w = t >> 6;
    int wr = w >> 1, wc = w & 1;
    int bid = blockIdx.x;                       // 1024 blocks
    int ag = bid & 7, qe = (bid >> 3) & 1, pe = (bid >> 4) & 1, n = bid >> 5;

    int aoff[8];
    #pragma unroll
    for (int i = 0; i < 8; ++i) {
        int row = (((w << 3) + i) << 2) + (lane >> 4);
        int slot = lane & 15;
        int a = (ag << 2) + (row >> 5), b = row & 31;
        int csw = (slot ^ (row & 7)) << 3;
        aoff[i] = (((n * 34 + (a + pe)) * 34 + (b + qe)) << 7) + csw;
    }

    f32x4 acc[4][4];
    #pragma unroll
    for (int mi = 0; mi < 4; ++mi)
        #pragma unroll
        for (int ni = 0; ni < 4; ++ni) acc[mi][ni] = (f32x4){0.f, 0.f, 0.f, 0.f};

    for (int tu = 0; tu < 4; ++tu) {
        __syncthreads();
        int tt = tu >> 1, u = tu & 1;
        int tapoff = ((tt * 34 + u) << 7);
        const __hip_bfloat16* wsl = w1s + ((((pe << 3) | (qe << 2) | tu)) << 14);
        #pragma unroll
        for (int i = 0; i < 8; ++i) {
            gload16(dq + aoff[i] + tapoff, &smem[((w << 3) + i) << 10]);
            gload16(wsl + ((((w << 3) + i) << 9) + (lane << 3)), &smem[32768 + (((w << 3) + i) << 10)]);
        }
        __syncthreads();
        #pragma unroll
        for (int ks = 0; ks < 4; ++ks) {
            bf16x8 av[4], bv[4];
            #pragma unroll
            for (int mi = 0; mi < 4; ++mi)
                av[mi] = *(const bf16x8*)&smem[fragoff((wr << 6) + (mi << 4) + (lane & 15), ks, lane)];
            #pragma unroll
            for (int ni = 0; ni < 4; ++ni)
                bv[ni] = *(const bf16x8*)&smem[32768 + fragoff((wc << 6) + (ni << 4) + (lane & 15), ks, lane)];
            #pragma unroll
            for (int mi = 0; mi < 4; ++mi)
                #pragma unroll
                for (int ni = 0; ni < 4; ++ni)
                    acc[mi][ni] = __builtin_amdgcn_mfma_f32_16x16x32_bf16(av[mi], bv[ni], acc[mi][ni], 0, 0, 0);
        }
    }

    int rg = (lane >> 4) << 2;
    #pragma unroll
    for (int mi = 0; mi < 4; ++mi)
        #pragma unroll
        for (int ni = 0; ni < 4; ++ni) {
            int o = (wc << 6) + (ni << 4) + (lane & 15);
            float bias = b1[o];
            #pragma unroll
            for (int j = 0; j < 4; ++j) {
                int row = (wr << 6) + (mi << 4) + rg + j;
                int a = (ag << 2) + (row >> 5), b = row & 31;
                int y = 2 * a + pe, xx2 = 2 * b + qe;
                float v = acc[mi][ni][j] + bias;
                g[(((n * 64 + y) * 64 + xx2) << 7) + o] = v > 0.f ? v : 0.f;
            }
        }
}

// ---- deconv2 + sigmoid: g f32 NHWC -> out NCHW [32,3,128,128] ----
__global__ __launch_bounds__(128) void k_deconv2(
    const float* __restrict__ g, const float* __restrict__ w2dt,
    const float* __restrict__ b2, float* __restrict__ out)
{
    __shared__ float wl[2][2][2][128][4];
    int bid = blockIdx.x;                       // 4096 = n(32) * y(128)
    int y = bid & 127, n = bid >> 7;
    int pe = y & 1, a = y >> 1;
    int t = threadIdx.x;
    int qe = t >> 6, b = t & 63;

    for (int i = t; i < 3072; i += 128) {
        int o = i % 3; int rest = i / 3; int c = rest & 127; int m8 = rest >> 7;
        wl[m8 >> 2][(m8 >> 1) & 1][m8 & 1][c][o] =
            w2dt[((pe * 8 + m8) * 128 + c) * 3 + o];
    }
    __syncthreads();

    float a0 = 0.f, a1 = 0.f, a2 = 0.f;
    for (int tu = 0; tu < 4; ++tu) {
        int tt = tu >> 1, u = tu & 1;
        int iy = a + pe + tt - 1;
        int ix = b + qe + u - 1;
        if (((unsigned)iy < 64u) && ((unsigned)ix < 64u)) {
            const float* gr = g + ((n * 64 + iy) * 64 + ix) * 128;
            const float* wc = &wl[qe][tt][u][0][0];
            for (int c = 0; c < 128; c += 4) {
                float4 gv = *(const float4*)(gr + c);
                const float* w0 = wc + c * 4;
                a0 = fmaf(gv.x, w0[0],  a0); a1 = fmaf(gv.x, w0[1],  a1); a2 = fmaf(gv.x, w0[2],  a2);
                a0 = fmaf(gv.y, w0[4],  a0); a1 = fmaf(gv.y, w0[5],  a1); a2 = fmaf(gv.y, w0[6],  a2);
                a0 = fmaf(gv.z, w0[8],  a0); a1 = fmaf(gv.z, w0[9],  a1); a2 = fmaf(gv.z, w0[10], a2);
                a0 = fmaf(gv.w, w0[12], a0); a1 = fmaf(gv.w, w0[13], a1); a2 = fmaf(gv.w, w0[14], a2);
            }
        }
    }
    int x = 2 * b + qe;
    float v0 = 1.f / (1.f + expf(-(a0 + b2[0])));
    float v1 = 1.f / (1.f + expf(-(a1 + b2[1])));
    float v2 = 1.f / (1.f + expf(-(a2 + b2[2])));
    out[((n * 3 + 0) * 128 + y) * 128 + x] = v0;
    out[((n * 3 + 1) * 128 + y) * 128 + x] = v1;
    out[((n * 3 + 2) * 128 + y) * 128 + x] = v2;
}

extern "C" void kernel_launch(void* const* d_in, const int* in_sizes, int n_in,
                              void* d_out, int out_size, void* d_ws, size_t ws_size,
                              hipStream_t stream) {
    const float* x   = (const float*)d_in[0];
    const float* ew1 = (const float*)d_in[1];
    const float* eb1 = (const float*)d_in[2];
    const float* ew2 = (const float*)d_in[3];
    const float* eb2 = (const float*)d_in[4];
    const float* E   = (const float*)d_in[5];
    const float* dw1 = (const float*)d_in[6];
    const float* db1 = (const float*)d_in[7];
    const float* dw2 = (const float*)d_in[8];
    const float* db2 = (const float*)d_in[9];
    float* out = (float*)d_out;

    char* W = (char*)d_ws;
    __hip_bfloat16* hb  = (__hip_bfloat16*)(W + 0);
    float*          g   = (float*)(W + 0);            // union with hb (hb dead after conv2)
    __hip_bfloat16* zb  = (__hip_bfloat16*)(W + 67108864);
    __hip_bfloat16* dq  = (__hip_bfloat16*)(W + 75497472);
    __hip_bfloat16* w2s = (__hip_bfloat16*)(W + 84967424);
    __hip_bfloat16* w1s = (__hip_bfloat16*)(W + 85491712);
    __hip_bfloat16* Eb  = (__hip_bfloat16*)(W + 86016000);
    float*          w2d = (float*)(W + 86147072);
    float*          s2  = (float*)(W + 86171648);
    int*            idx = (int*)(W + 86173696);

    k_prep_w2s  <<<1024, 256, 0, stream>>>(ew2, w2s);
    k_prep_w1s  <<<1024, 256, 0, stream>>>(dw1, w1s);
    k_prep_Eb   <<<256,  256, 0, stream>>>(E, Eb);
    k_prep_w2dt <<<24,   256, 0, stream>>>(dw2, w2d);
    k_prep_sumE2<<<2,    256, 0, stream>>>(E, s2);

    k_conv1  <<<69696, 256, 0, stream>>>(x, ew1, eb1, hb);
    k_conv2  <<<256,   256, 0, stream>>>(hb, w2s, eb2, zb);
    k_vq     <<<256,   256, 0, stream>>>(zb, Eb, s2, idx);
    k_scatter<<<18496, 256, 0, stream>>>(E, idx, dq);
    k_deconv1<<<1024,  256, 0, stream>>>(dq, w1s, db1, g);
    k_deconv2<<<4096,  128, 0, stream>>>(g, w2d, db2, out);
}

// Round 3
// 231.011 us; speedup vs baseline: 11.1494x; 2.4148x over previous
//
#include <hip/hip_runtime.h>
#include <hip/hip_bf16.h>
#include <math.h>

// ---------------------------------------------------------------------------
// VQ-VAE forward. conv1 / conv2 / deconv1 / vq are bf16 MFMA implicit GEMMs
// (128x128 tile, global_load_lds staging or fused im2col reg-staging,
//  XOR-swizzled LDS). deconv2 is a bf16 vector kernel on padded g.
// ws layout (bytes):
//   0          : hb   bf16 [32][66][66][128] (padded conv1 out)  35,684,352
//                g    bf16 [32][66][66][128] (padded deconv1 out, UNION)
//   67108864   : zb   bf16 [32768][128]                           8,388,608
//   75497472   : dq   bf16 [32][34][34][128] (padded scatter out) 9,469,952
//   84967424   : w2s  bf16 [16 rs][128 o][128 c] pre-swizzled       524,288
//   85491712   : w1s  bf16 [16 m ][128 o][128 c] pre-swizzled       524,288
//   86016000   : Eb   bf16 [512 k][128 c]  pre-swizzled             131,072
//   86147072   : w2d  f32  [6144]                                    24,576
//   86171648   : s2   f32  [512]                                      2,048
//   86173696   : idx  int  [32768]                                  131,072
//   86304768   : w1b  bf16 [128 o][64 K] pre-swizzled (conv1)        16,384
// total ~86.3 MB
// ---------------------------------------------------------------------------

typedef __attribute__((ext_vector_type(8))) short bf16x8;
typedef __attribute__((ext_vector_type(8))) unsigned short u16x8;
typedef __attribute__((ext_vector_type(4))) float f32x4;

__device__ __forceinline__ void gload16(const void* g, const void* l) {
    __builtin_amdgcn_global_load_lds(
        (const __attribute__((address_space(1))) void*)g,
        (__attribute__((address_space(3))) void*)l, 16, 0, 0);
}

// byte offset of the 16B fragment (row, k-sub ks) in a swizzled 128x128 bf16 tile
__device__ __forceinline__ int fragoff(int row, int ks, int lane) {
    return (row << 8) + (((ks << 6) + (lane & 0x30)) ^ ((row & 7) << 4));
}
// same for a 128x64 tile (128B rows), ks in {0,1}
__device__ __forceinline__ int fragoff64(int row, int ks, int lane) {
    return (row << 7) + (((ks << 6) + (lane & 0x30)) ^ ((row & 7) << 4));
}

__device__ __forceinline__ float bf2f(unsigned short u) {
    union { unsigned int i; float f; } v; v.i = ((unsigned int)u) << 16; return v.f;
}

// ---- border zero-fill for hb/g padded [32][66][66][128] ----
__global__ __launch_bounds__(256) void k_border(__hip_bfloat16* __restrict__ hb)
{
    int tid = blockIdx.x * 256 + threadIdx.x;       // 1,064,960 = 4160*256
    const int NROW = 32 * 2 * 66 * 128;             // 540,672
    if (tid < NROW) {
        int c = tid & 127;
        int xx = (tid >> 7) % 66;
        int r2 = tid / (66 * 128);
        int yy = (r2 & 1) * 65;
        int n = r2 >> 1;
        hb[((n * 66 + yy) * 66 + xx) * 128 + c] = __float2bfloat16(0.f);
    } else {
        int t2 = tid - NROW;                        // < 524,288
        int c = t2 & 127;
        int xs = (t2 >> 7) & 1;
        int yy = ((t2 >> 8) & 63) + 1;
        int n = t2 >> 14;
        hb[((n * 66 + yy) * 66 + xs * 65) * 128 + c] = __float2bfloat16(0.f);
    }
}

// ---- conv1 as MFMA implicit GEMM with fused im2col staging ----
// M=131072 positions, K=48 (pad 64), N=128.  grid 1024, block 256.
__global__ __launch_bounds__(256) void k_conv1g(
    const float* __restrict__ x, const __hip_bfloat16* __restrict__ w1b,
    const float* __restrict__ b1, __hip_bfloat16* __restrict__ hb)
{
    __shared__ char smem[32768];                    // A 16KB | B 16KB
    int t = threadIdx.x, lane = t & 63, w = t >> 6;
    int wr = w >> 1, wc = w & 1;
    int posbase = blockIdx.x << 7;

    // B staging: w1b [128 o][64 K] pre-swizzled, row-linear
    #pragma unroll
    for (int i = 0; i < 4; ++i)
        gload16(w1b + ((w * 4 + i) * 512 + lane * 8), &smem[16384 + ((w * 4 + i) << 10)]);

    // A staging: fused im2col.  thread t covers row=t>>1 (128B), half=t&1 (4 slots)
    {
        int row = t >> 1, half = t & 1;
        int rowg = posbase + row;
        int n = rowg >> 12, p = (rowg >> 6) & 63, q = rowg & 63;
        #pragma unroll
        for (int j = 0; j < 4; ++j) {
            int d = half * 4 + j;                   // dest slot
            int sct = d ^ (row & 7);                // content slot
            __hip_bfloat16 hv[8];
            #pragma unroll
            for (int e = 0; e < 8; ++e) {
                int k = sct * 8 + e;
                float v = 0.f;
                if (k < 48) {
                    int c = k >> 4, r = (k >> 2) & 3, s4 = k & 3;
                    int y = 2 * p + r - 1, xx = 2 * q + s4 - 1;
                    if (((unsigned)y < 128u) && ((unsigned)xx < 128u))
                        v = x[((n * 3 + c) * 128 + y) * 128 + xx];
                }
                hv[e] = __float2bfloat16(v);
            }
            *(bf16x8*)&smem[(row << 7) + d * 16] = *(bf16x8*)hv;
        }
    }
    __syncthreads();

    f32x4 acc[4][4];
    #pragma unroll
    for (int mi = 0; mi < 4; ++mi)
        #pragma unroll
        for (int ni = 0; ni < 4; ++ni) acc[mi][ni] = (f32x4){0.f, 0.f, 0.f, 0.f};

    #pragma unroll
    for (int ks = 0; ks < 2; ++ks) {
        bf16x8 av[4], bv[4];
        #pragma unroll
        for (int mi = 0; mi < 4; ++mi)
            av[mi] = *(const bf16x8*)&smem[fragoff64((wr << 6) + (mi << 4) + (lane & 15), ks, lane)];
        #pragma unroll
        for (int ni = 0; ni < 4; ++ni)
            bv[ni] = *(const bf16x8*)&smem[16384 + fragoff64((wc << 6) + (ni << 4) + (lane & 15), ks, lane)];
        #pragma unroll
        for (int mi = 0; mi < 4; ++mi)
            #pragma unroll
            for (int ni = 0; ni < 4; ++ni)
                acc[mi][ni] = __builtin_amdgcn_mfma_f32_16x16x32_bf16(av[mi], bv[ni], acc[mi][ni], 0, 0, 0);
    }

    int rg = (lane >> 4) << 2;
    #pragma unroll
    for (int mi = 0; mi < 4; ++mi)
        #pragma unroll
        for (int ni = 0; ni < 4; ++ni) {
            int o = (wc << 6) + (ni << 4) + (lane & 15);
            float bias = b1[o];
            #pragma unroll
            for (int j = 0; j < 4; ++j) {
                int rowg = posbase + (wr << 6) + (mi << 4) + rg + j;
                int n = rowg >> 12, p = (rowg >> 6) & 63, q = rowg & 63;
                float v = acc[mi][ni][j] + bias;
                v = v > 0.f ? v : 0.f;
                hb[((n * 66 + p + 1) * 66 + q + 1) * 128 + o] = __float2bfloat16(v);
            }
        }
}

// ---- weight/codebook prep (pre-swizzled bf16 layouts) ----
__global__ void k_prep_w2s(const float* __restrict__ ew2, __hip_bfloat16* __restrict__ w2s) {
    int tid = blockIdx.x * 256 + threadIdx.x;   // 262144
    int cpos = tid & 127, o = (tid >> 7) & 127, rs = tid >> 14;
    int r = rs >> 2, s = rs & 3;
    int slot = cpos >> 3, e = cpos & 7;
    int csrc = ((slot ^ (o & 7)) << 3) | e;
    w2s[tid] = __float2bfloat16(ew2[((o * 128 + csrc) * 4 + r) * 4 + s]);
}

__global__ void k_prep_w1s(const float* __restrict__ dw1, __hip_bfloat16* __restrict__ w1s) {
    int tid = blockIdx.x * 256 + threadIdx.x;   // 262144
    int cpos = tid & 127, o = (tid >> 7) & 127, m = tid >> 14;
    int pe = (m >> 3) & 1, qe = (m >> 2) & 1, tt = (m >> 1) & 1, u = m & 1;
    int slot = cpos >> 3, e = cpos & 7;
    int csrc = ((slot ^ (o & 7)) << 3) | e;
    w1s[tid] = __float2bfloat16(dw1[((o * 128 + csrc) * 4 + (pe + 2 * tt)) * 4 + (qe + 2 * u)]);
}

__global__ void k_prep_Eb(const float* __restrict__ E, __hip_bfloat16* __restrict__ Eb) {
    int tid = blockIdx.x * 256 + threadIdx.x;   // 65536
    int cpos = tid & 127, k = tid >> 7;
    int slot = cpos >> 3, e = cpos & 7;
    int csrc = ((slot ^ (k & 7)) << 3) | e;
    Eb[tid] = __float2bfloat16(E[k * 128 + csrc]);
}

__global__ void k_prep_w1b(const float* __restrict__ ew1, __hip_bfloat16* __restrict__ w1b) {
    int tid = blockIdx.x * 256 + threadIdx.x;   // 8192
    if (tid >= 8192) return;
    int o = tid >> 6, cpos = tid & 63;
    int slot = cpos >> 3, e = cpos & 7;
    int k = ((slot ^ (o & 7)) << 3) | e;
    float v = 0.f;
    if (k < 48) {
        int c = k >> 4, r = (k >> 2) & 3, s = k & 3;
        v = ew1[((o * 3 + c) * 4 + r) * 4 + s];
    }
    w1b[tid] = __float2bfloat16(v);
}

__global__ void k_prep_w2dt(const float* __restrict__ dw2, float* __restrict__ w2dt) {
    int tid = blockIdx.x * 256 + threadIdx.x;   // 6144
    if (tid >= 6144) return;
    int o = tid % 3; int rest = tid / 3; int c = rest & 127; int m = rest >> 7;
    int pe = (m >> 3) & 1, qe = (m >> 2) & 1, t = (m >> 1) & 1, u = m & 1;
    w2dt[tid] = dw2[((o * 128 + c) * 4 + (pe + 2 * t)) * 4 + (qe + 2 * u)];
}

__global__ void k_prep_sumE2(const float* __restrict__ E, float* __restrict__ s2) {
    int k = blockIdx.x * 256 + threadIdx.x;     // 512
    float a = 0.f;
    const float* e = E + k * 128;
    for (int c = 0; c < 128; ++c) a = fmaf(e[c], e[c], a);
    s2[k] = a;
}

// ---- conv2: hb (padded bf16) -> zb bf16 [32768][128] ----
__global__ __launch_bounds__(256) void k_conv2(
    const __hip_bfloat16* __restrict__ hb, const __hip_bfloat16* __restrict__ w2s,
    const float* __restrict__ b2, __hip_bfloat16* __restrict__ zb)
{
    __shared__ char smem[65536];
    int t = threadIdx.x, lane = t & 63, w = t >> 6;
    int wr = w >> 1, wc = w & 1;
    int posbase = blockIdx.x << 7;              // 256 blocks
    int n = posbase >> 10, prow0 = (posbase >> 5) & 31;

    int aoff[8];
    #pragma unroll
    for (int i = 0; i < 8; ++i) {
        int row = (((w << 3) + i) << 2) + (lane >> 4);
        int slot = lane & 15;
        int p = prow0 + (row >> 5), q = row & 31;
        int csw = (slot ^ (row & 7)) << 3;
        aoff[i] = (((n * 66 + 2 * p) * 66 + 2 * q) << 7) + csw;
    }

    f32x4 acc[4][4];
    #pragma unroll
    for (int mi = 0; mi < 4; ++mi)
        #pragma unroll
        for (int ni = 0; ni < 4; ++ni) acc[mi][ni] = (f32x4){0.f, 0.f, 0.f, 0.f};

    for (int rs = 0; rs < 16; ++rs) {
        __syncthreads();
        int rsoff = (((rs >> 2) * 66 + (rs & 3)) << 7);
        const __hip_bfloat16* wsl = w2s + (rs << 14);
        #pragma unroll
        for (int i = 0; i < 8; ++i) {
            gload16(hb + aoff[i] + rsoff, &smem[((w << 3) + i) << 10]);
            gload16(wsl + ((((w << 3) + i) << 9) + (lane << 3)), &smem[32768 + (((w << 3) + i) << 10)]);
        }
        __syncthreads();
        #pragma unroll
        for (int ks = 0; ks < 4; ++ks) {
            bf16x8 av[4], bv[4];
            #pragma unroll
            for (int mi = 0; mi < 4; ++mi)
                av[mi] = *(const bf16x8*)&smem[fragoff((wr << 6) + (mi << 4) + (lane & 15), ks, lane)];
            #pragma unroll
            for (int ni = 0; ni < 4; ++ni)
                bv[ni] = *(const bf16x8*)&smem[32768 + fragoff((wc << 6) + (ni << 4) + (lane & 15), ks, lane)];
            #pragma unroll
            for (int mi = 0; mi < 4; ++mi)
                #pragma unroll
                for (int ni = 0; ni < 4; ++ni)
                    acc[mi][ni] = __builtin_amdgcn_mfma_f32_16x16x32_bf16(av[mi], bv[ni], acc[mi][ni], 0, 0, 0);
        }
    }

    int rg = (lane >> 4) << 2;
    #pragma unroll
    for (int mi = 0; mi < 4; ++mi)
        #pragma unroll
        for (int ni = 0; ni < 4; ++ni) {
            int o = (wc << 6) + (ni << 4) + (lane & 15);
            float bias = b2[o];
            #pragma unroll
            for (int j = 0; j < 4; ++j) {
                int pos = posbase + (wr << 6) + (mi << 4) + rg + j;
                zb[(pos << 7) + o] = __float2bfloat16(acc[mi][ni][j] + bias);
            }
        }
}

// ---- vq: zb bf16 x Eb bf16 MFMA, fused argmin -> idx ----
__global__ __launch_bounds__(256) void k_vq(
    const __hip_bfloat16* __restrict__ zb, const __hip_bfloat16* __restrict__ Eb,
    const float* __restrict__ s2, int* __restrict__ idxout)
{
    __shared__ char smem[65536];
    int t = threadIdx.x, lane = t & 63, w = t >> 6;
    int wr = w >> 1, wc = w & 1;
    int posbase = blockIdx.x << 7;              // 256 blocks

    #pragma unroll
    for (int i = 0; i < 8; ++i) {
        int row = (((w << 3) + i) << 2) + (lane >> 4);
        int slot = lane & 15;
        int csw = (slot ^ (row & 7)) << 3;
        gload16(zb + (((posbase + row) << 7) + csw), &smem[((w << 3) + i) << 10]);
    }

    float bvv[4][4];
    int   bii[4][4];
    #pragma unroll
    for (int mi = 0; mi < 4; ++mi)
        #pragma unroll
        for (int j = 0; j < 4; ++j) { bvv[mi][j] = 3.4e38f; bii[mi][j] = 0; }

    for (int n0 = 0; n0 < 4; ++n0) {
        __syncthreads();
        const __hip_bfloat16* esl = Eb + (n0 << 14);
        #pragma unroll
        for (int i = 0; i < 8; ++i)
            gload16(esl + ((((w << 3) + i) << 9) + (lane << 3)), &smem[32768 + (((w << 3) + i) << 10)]);
        __syncthreads();

        f32x4 acc[4][4];
        #pragma unroll
        for (int mi = 0; mi < 4; ++mi)
            #pragma unroll
            for (int ni = 0; ni < 4; ++ni) acc[mi][ni] = (f32x4){0.f, 0.f, 0.f, 0.f};

        #pragma unroll
        for (int ks = 0; ks < 4; ++ks) {
            bf16x8 av[4], bv[4];
            #pragma unroll
            for (int mi = 0; mi < 4; ++mi)
                av[mi] = *(const bf16x8*)&smem[fragoff((wr << 6) + (mi << 4) + (lane & 15), ks, lane)];
            #pragma unroll
            for (int ni = 0; ni < 4; ++ni)
                bv[ni] = *(const bf16x8*)&smem[32768 + fragoff((wc << 6) + (ni << 4) + (lane & 15), ks, lane)];
            #pragma unroll
            for (int mi = 0; mi < 4; ++mi)
                #pragma unroll
                for (int ni = 0; ni < 4; ++ni)
                    acc[mi][ni] = __builtin_amdgcn_mfma_f32_16x16x32_bf16(av[mi], bv[ni], acc[mi][ni], 0, 0, 0);
        }

        float s2v[4];
        #pragma unroll
        for (int ni = 0; ni < 4; ++ni)
            s2v[ni] = s2[(n0 << 7) + (wc << 6) + (ni << 4) + (lane & 15)];
        #pragma unroll
        for (int mi = 0; mi < 4; ++mi)
            #pragma unroll
            for (int ni = 0; ni < 4; ++ni) {
                int k = (n0 << 7) + (wc << 6) + (ni << 4) + (lane & 15);
                #pragma unroll
                for (int j = 0; j < 4; ++j) {
                    float sc = s2v[ni] - 2.f * acc[mi][ni][j];
                    if (sc < bvv[mi][j]) { bvv[mi][j] = sc; bii[mi][j] = k; }
                }
            }
    }

    __syncthreads();
    float* redv = (float*)smem;
    int*   redi = (int*)(smem + 1024);
    #pragma unroll
    for (int mi = 0; mi < 4; ++mi)
        #pragma unroll
        for (int j = 0; j < 4; ++j) {
            float v = bvv[mi][j];
            int   ix = bii[mi][j];
            #pragma unroll
            for (int m = 1; m < 16; m <<= 1) {
                float ov = __shfl_xor(v, m, 64);
                int   oi = __shfl_xor(ix, m, 64);
                if (ov < v || (ov == v && oi < ix)) { v = ov; ix = oi; }
            }
            if ((lane & 15) == 0) {
                int row = (wr << 6) + (mi << 4) + ((lane >> 4) << 2) + j;
                redv[row * 2 + wc] = v;
                redi[row * 2 + wc] = ix;
            }
        }
    __syncthreads();
    if (t < 128) {
        float v0 = redv[t * 2], v1 = redv[t * 2 + 1];
        int   i0 = redi[t * 2], i1 = redi[t * 2 + 1];
        int best = (v1 < v0 || (v1 == v0 && i1 < i0)) ? i1 : i0;
        idxout[posbase + t] = best;
    }
}

// ---- scatter: dq bf16 padded [32,34,34,128] <- E[idx] (no-permute reshape) ----
__global__ void k_scatter(const float* __restrict__ E, const int* __restrict__ idx,
                          __hip_bfloat16* __restrict__ dq)
{
    int tid = blockIdx.x * 256 + threadIdx.x;   // 32*34*34*128 = 4,734,976
    int c = tid & 127;
    int rest = tid >> 7;
    int xx = rest % 34;
    int t2 = rest / 34;
    int yy = t2 % 34;
    int n = t2 / 34;
    float v = 0.f;
    if (yy >= 1 && yy <= 32 && xx >= 1 && xx <= 32) {
        int y = yy - 1, x = xx - 1;
        int pos = (y << 5) | x;
        int row = (n << 10) + (c << 3) + (pos >> 7);
        int col = pos & 127;
        v = E[idx[row] * 128 + col];
    }
    dq[tid] = __float2bfloat16(v);
}

// ---- deconv1: dq (padded bf16) -> relu -> g bf16 padded [32,66,66,128] ----
__global__ __launch_bounds__(256) void k_deconv1(
    const __hip_bfloat16* __restrict__ dq, const __hip_bfloat16* __restrict__ w1s,
    const float* __restrict__ b1, __hip_bfloat16* __restrict__ g)
{
    __shared__ char smem[65536];
    int t = threadIdx.x, lane = t & 63, w = t >> 6;
    int wr = w >> 1, wc = w & 1;
    int bid = blockIdx.x;                       // 1024 blocks
    int ag = bid & 7, qe = (bid >> 3) & 1, pe = (bid >> 4) & 1, n = bid >> 5;

    int aoff[8];
    #pragma unroll
    for (int i = 0; i < 8; ++i) {
        int row = (((w << 3) + i) << 2) + (lane >> 4);
        int slot = lane & 15;
        int a = (ag << 2) + (row >> 5), b = row & 31;
        int csw = (slot ^ (row & 7)) << 3;
        aoff[i] = (((n * 34 + (a + pe)) * 34 + (b + qe)) << 7) + csw;
    }

    f32x4 acc[4][4];
    #pragma unroll
    for (int mi = 0; mi < 4; ++mi)
        #pragma unroll
        for (int ni = 0; ni < 4; ++ni) acc[mi][ni] = (f32x4){0.f, 0.f, 0.f, 0.f};

    for (int tu = 0; tu < 4; ++tu) {
        __syncthreads();
        int tt = tu >> 1, u = tu & 1;
        int tapoff = ((tt * 34 + u) << 7);
        const __hip_bfloat16* wsl = w1s + ((((pe << 3) | (qe << 2) | tu)) << 14);
        #pragma unroll
        for (int i = 0; i < 8; ++i) {
            gload16(dq + aoff[i] + tapoff, &smem[((w << 3) + i) << 10]);
            gload16(wsl + ((((w << 3) + i) << 9) + (lane << 3)), &smem[32768 + (((w << 3) + i) << 10)]);
        }
        __syncthreads();
        #pragma unroll
        for (int ks = 0; ks < 4; ++ks) {
            bf16x8 av[4], bv[4];
            #pragma unroll
            for (int mi = 0; mi < 4; ++mi)
                av[mi] = *(const bf16x8*)&smem[fragoff((wr << 6) + (mi << 4) + (lane & 15), ks, lane)];
            #pragma unroll
            for (int ni = 0; ni < 4; ++ni)
                bv[ni] = *(const bf16x8*)&smem[32768 + fragoff((wc << 6) + (ni << 4) + (lane & 15), ks, lane)];
            #pragma unroll
            for (int mi = 0; mi < 4; ++mi)
                #pragma unroll
                for (int ni = 0; ni < 4; ++ni)
                    acc[mi][ni] = __builtin_amdgcn_mfma_f32_16x16x32_bf16(av[mi], bv[ni], acc[mi][ni], 0, 0, 0);
        }
    }

    int rg = (lane >> 4) << 2;
    #pragma unroll
    for (int mi = 0; mi < 4; ++mi)
        #pragma unroll
        for (int ni = 0; ni < 4; ++ni) {
            int o = (wc << 6) + (ni << 4) + (lane & 15);
            float bias = b1[o];
            #pragma unroll
            for (int j = 0; j < 4; ++j) {
                int row = (wr << 6) + (mi << 4) + rg + j;
                int a = (ag << 2) + (row >> 5), b = row & 31;
                int y = 2 * a + pe, xx2 = 2 * b + qe;
                float v = acc[mi][ni][j] + bias;
                v = v > 0.f ? v : 0.f;
                g[((n * 66 + y + 1) * 66 + xx2 + 1) * 128 + o] = __float2bfloat16(v);
            }
        }
}

// ---- deconv2 + sigmoid: g bf16 padded -> out NCHW [32,3,128,128] fp32 ----
__global__ __launch_bounds__(128) void k_deconv2(
    const __hip_bfloat16* __restrict__ g, const float* __restrict__ w2dt,
    const float* __restrict__ b2, float* __restrict__ out)
{
    __shared__ float wl[2][2][2][128][4];       // [qe][t][u][c][o(3)+pad]
    int bid = blockIdx.x;                       // 4096 = n(32) * y(128)
    int y = bid & 127, n = bid >> 7;
    int pe = y & 1, a = y >> 1;
    int t = threadIdx.x;
    int qe = t >> 6, b = t & 63;

    for (int i = t; i < 3072; i += 128) {
        int o = i % 3; int rest = i / 3; int c = rest & 127; int m8 = rest >> 7;
        wl[m8 >> 2][(m8 >> 1) & 1][m8 & 1][c][o] =
            w2dt[((pe * 8 + m8) * 128 + c) * 3 + o];
    }
    __syncthreads();

    float a0 = 0.f, a1 = 0.f, a2 = 0.f;
    #pragma unroll
    for (int tu = 0; tu < 4; ++tu) {
        int tt = tu >> 1, u = tu & 1;
        const unsigned short* gr = (const unsigned short*)g
            + ((n * 66 + (a + pe + tt)) * 66 + (b + qe + u)) * 128;
        const float* wc = &wl[qe][tt][u][0][0];
        for (int c = 0; c < 128; c += 8) {
            u16x8 gv = *(const u16x8*)(gr + c);
            #pragma unroll
            for (int jj = 0; jj < 8; ++jj) {
                float gf = bf2f(gv[jj]);
                float4 wv = *(const float4*)(wc + (c + jj) * 4);
                a0 = fmaf(gf, wv.x, a0);
                a1 = fmaf(gf, wv.y, a1);
                a2 = fmaf(gf, wv.z, a2);
            }
        }
    }
    int x = 2 * b + qe;
    float v0 = 1.f / (1.f + expf(-(a0 + b2[0])));
    float v1 = 1.f / (1.f + expf(-(a1 + b2[1])));
    float v2 = 1.f / (1.f + expf(-(a2 + b2[2])));
    out[((n * 3 + 0) * 128 + y) * 128 + x] = v0;
    out[((n * 3 + 1) * 128 + y) * 128 + x] = v1;
    out[((n * 3 + 2) * 128 + y) * 128 + x] = v2;
}

extern "C" void kernel_launch(void* const* d_in, const int* in_sizes, int n_in,
                              void* d_out, int out_size, void* d_ws, size_t ws_size,
                              hipStream_t stream) {
    const float* x   = (const float*)d_in[0];
    const float* ew1 = (const float*)d_in[1];
    const float* eb1 = (const float*)d_in[2];
    const float* ew2 = (const float*)d_in[3];
    const float* eb2 = (const float*)d_in[4];
    const float* E   = (const float*)d_in[5];
    const float* dw1 = (const float*)d_in[6];
    const float* db1 = (const float*)d_in[7];
    const float* dw2 = (const float*)d_in[8];
    const float* db2 = (const float*)d_in[9];
    float* out = (float*)d_out;

    char* W = (char*)d_ws;
    __hip_bfloat16* hb  = (__hip_bfloat16*)(W + 0);
    __hip_bfloat16* g   = (__hip_bfloat16*)(W + 0);   // union: hb dead after conv2
    __hip_bfloat16* zb  = (__hip_bfloat16*)(W + 67108864);
    __hip_bfloat16* dq  = (__hip_bfloat16*)(W + 75497472);
    __hip_bfloat16* w2s = (__hip_bfloat16*)(W + 84967424);
    __hip_bfloat16* w1s = (__hip_bfloat16*)(W + 85491712);
    __hip_bfloat16* Eb  = (__hip_bfloat16*)(W + 86016000);
    float*          w2d = (float*)(W + 86147072);
    float*          s2  = (float*)(W + 86171648);
    int*            idx = (int*)(W + 86173696);
    __hip_bfloat16* w1b = (__hip_bfloat16*)(W + 86304768);

    k_prep_w2s  <<<1024, 256, 0, stream>>>(ew2, w2s);
    k_prep_w1s  <<<1024, 256, 0, stream>>>(dw1, w1s);
    k_prep_Eb   <<<256,  256, 0, stream>>>(E, Eb);
    k_prep_w1b  <<<32,   256, 0, stream>>>(ew1, w1b);
    k_prep_w2dt <<<24,   256, 0, stream>>>(dw2, w2d);
    k_prep_sumE2<<<2,    256, 0, stream>>>(E, s2);

    k_border <<<4160,  256, 0, stream>>>(hb);
    k_conv1g <<<1024,  256, 0, stream>>>(x, w1b, eb1, hb);
    k_conv2  <<<256,   256, 0, stream>>>(hb, w2s, eb2, zb);
    k_vq     <<<256,   256, 0, stream>>>(zb, Eb, s2, idx);
    k_scatter<<<18496, 256, 0, stream>>>(E, idx, dq);
    k_deconv1<<<1024,  256, 0, stream>>>(dq, w1s, db1, g);
    k_deconv2<<<4096,  128, 0, stream>>>(g, w2d, db2, out);
}

// Round 4
// 164.209 us; speedup vs baseline: 15.6852x; 1.4068x over previous
//
#include <hip/hip_runtime.h>
#include <hip/hip_bf16.h>
#include <math.h>

// ---------------------------------------------------------------------------
// VQ-VAE forward. conv1 / conv2 / deconv1 / deconv2 / vq are bf16 MFMA
// implicit GEMMs (128-row tiles, global_load_lds staging or fused im2col,
// XOR-swizzled LDS). One k_init dispatch does all weight prep + border fill.
// ws layout (bytes):
//   0          : hb   bf16 [32][66][66][128] (padded conv1 out)  35,684,352
//                g    bf16 [32][66][66][128] (padded deconv1 out, UNION)
//   67108864   : zb   bf16 [32768][128]                           8,388,608
//   75497472   : dq   bf16 [32][34][34][128] (padded scatter out) 9,469,952
//   84967424   : w2s  bf16 [16 rs][128 o][128 c] pre-swizzled       524,288
//   85491712   : w1s  bf16 [16 m ][128 o][128 c] pre-swizzled       524,288
//   86016000   : Eb   bf16 [512 k][128 c]  pre-swizzled             131,072
//   86147072   : w2db bf16 [4 pq][4 tu][16 o][128 c] pre-swizzled    65,536
//   86212608   : s2   f32  [512]                                      2,048
//   86214656   : idx  int  [32768]                                  131,072
//   86345728   : w1b  bf16 [128 o][64 K] pre-swizzled (conv1)        16,384
// ---------------------------------------------------------------------------

typedef __attribute__((ext_vector_type(8))) short bf16x8;
typedef __attribute__((ext_vector_type(4))) float f32x4;

__device__ __forceinline__ void gload16(const void* g, const void* l) {
    __builtin_amdgcn_global_load_lds(
        (const __attribute__((address_space(1))) void*)g,
        (__attribute__((address_space(3))) void*)l, 16, 0, 0);
}

// byte offset of the 16B fragment (row, k-sub ks) in a swizzled 128x128 bf16 tile
__device__ __forceinline__ int fragoff(int row, int ks, int lane) {
    return (row << 8) + (((ks << 6) + (lane & 0x30)) ^ ((row & 7) << 4));
}
// same for a 128x64 tile (128B rows), ks in {0,1}
__device__ __forceinline__ int fragoff64(int row, int ks, int lane) {
    return (row << 7) + (((ks << 6) + (lane & 0x30)) ^ ((row & 7) << 4));
}

// ---- k_init: border zero-fill + all weight/codebook prep in one dispatch ----
__global__ __launch_bounds__(256) void k_init(
    const float* __restrict__ ew1, const float* __restrict__ ew2,
    const float* __restrict__ E,   const float* __restrict__ dw1,
    const float* __restrict__ dw2,
    __hip_bfloat16* __restrict__ hb,  __hip_bfloat16* __restrict__ w2s,
    __hip_bfloat16* __restrict__ w1s, __hip_bfloat16* __restrict__ Eb,
    __hip_bfloat16* __restrict__ w1b, __hip_bfloat16* __restrict__ w2db,
    float* __restrict__ s2)
{
    int bid = blockIdx.x, t = threadIdx.x;
    if (bid < 4160) {                               // border fill of hb/g ring
        int tid = bid * 256 + t;                    // 1,064,960
        const int NROW = 32 * 2 * 66 * 128;
        if (tid < NROW) {
            int c = tid & 127;
            int xx = (tid >> 7) % 66;
            int r2 = tid / (66 * 128);
            int yy = (r2 & 1) * 65;
            int n = r2 >> 1;
            hb[((n * 66 + yy) * 66 + xx) * 128 + c] = __float2bfloat16(0.f);
        } else {
            int t2 = tid - NROW;                    // < 524,288
            int c = t2 & 127;
            int xs = (t2 >> 7) & 1;
            int yy = ((t2 >> 8) & 63) + 1;
            int n = t2 >> 14;
            hb[((n * 66 + yy) * 66 + xs * 65) * 128 + c] = __float2bfloat16(0.f);
        }
    } else if (bid < 5184) {                        // w2s
        int tid = (bid - 4160) * 256 + t;           // 262144
        int cpos = tid & 127, o = (tid >> 7) & 127, rs = tid >> 14;
        int r = rs >> 2, s = rs & 3;
        int slot = cpos >> 3, e = cpos & 7;
        int csrc = ((slot ^ (o & 7)) << 3) | e;
        w2s[tid] = __float2bfloat16(ew2[((o * 128 + csrc) * 4 + r) * 4 + s]);
    } else if (bid < 6208) {                        // w1s
        int tid = (bid - 5184) * 256 + t;           // 262144
        int cpos = tid & 127, o = (tid >> 7) & 127, m = tid >> 14;
        int pe = (m >> 3) & 1, qe = (m >> 2) & 1, tt = (m >> 1) & 1, u = m & 1;
        int slot = cpos >> 3, e = cpos & 7;
        int csrc = ((slot ^ (o & 7)) << 3) | e;
        w1s[tid] = __float2bfloat16(dw1[((o * 128 + csrc) * 4 + (pe + 2 * tt)) * 4 + (qe + 2 * u)]);
    } else if (bid < 6464) {                        // Eb
        int tid = (bid - 6208) * 256 + t;           // 65536
        int cpos = tid & 127, k = tid >> 7;
        int slot = cpos >> 3, e = cpos & 7;
        int csrc = ((slot ^ (k & 7)) << 3) | e;
        Eb[tid] = __float2bfloat16(E[k * 128 + csrc]);
    } else if (bid < 6496) {                        // w1b (conv1 weights, K=64 pad)
        int tid = (bid - 6464) * 256 + t;           // 8192
        int o = tid >> 6, cpos = tid & 63;
        int slot = cpos >> 3, e = cpos & 7;
        int k = ((slot ^ (o & 7)) << 3) | e;
        float v = 0.f;
        if (k < 48) {
            int c = k >> 4, r = (k >> 2) & 3, s = k & 3;
            v = ew1[((o * 3 + c) * 4 + r) * 4 + s];
        }
        w1b[tid] = __float2bfloat16(v);
    } else if (bid < 6624) {                        // w2db (deconv2, N pad 3->16)
        int tid = (bid - 6496) * 256 + t;           // 32768
        int cpos = tid & 127;
        int orow = (tid >> 7) & 15;
        int tu = (tid >> 11) & 3;
        int pq = tid >> 13;
        float v = 0.f;
        if (orow < 3) {
            int pe = pq >> 1, qe = pq & 1, tt = tu >> 1, u = tu & 1;
            int slot = cpos >> 3, e = cpos & 7;
            int csrc = ((slot ^ (orow & 7)) << 3) | e;
            v = dw2[((orow * 128 + csrc) * 4 + (pe + 2 * tt)) * 4 + (qe + 2 * u)];
        }
        w2db[tid] = __float2bfloat16(v);
    } else {                                        // sumE2
        int k = (bid - 6624) * 256 + t;             // 512
        float a = 0.f;
        const float* e = E + k * 128;
        for (int c = 0; c < 128; ++c) a = fmaf(e[c], e[c], a);
        s2[k] = a;
    }
}

// ---- conv1 as MFMA implicit GEMM with fused im2col staging ----
__global__ __launch_bounds__(256) void k_conv1g(
    const float* __restrict__ x, const __hip_bfloat16* __restrict__ w1b,
    const float* __restrict__ b1, __hip_bfloat16* __restrict__ hb)
{
    __shared__ char smem[32768];                    // A 16KB | B 16KB
    int t = threadIdx.x, lane = t & 63, w = t >> 6;
    int wr = w >> 1, wc = w & 1;
    int posbase = blockIdx.x << 7;

    #pragma unroll
    for (int i = 0; i < 4; ++i)
        gload16(w1b + ((w * 4 + i) * 512 + lane * 8), &smem[16384 + ((w * 4 + i) << 10)]);

    {
        int row = t >> 1, half = t & 1;
        int rowg = posbase + row;
        int n = rowg >> 12, p = (rowg >> 6) & 63, q = rowg & 63;
        #pragma unroll
        for (int j = 0; j < 4; ++j) {
            int d = half * 4 + j;
            int sct = d ^ (row & 7);
            __hip_bfloat16 hv[8];
            #pragma unroll
            for (int e = 0; e < 8; ++e) {
                int k = sct * 8 + e;
                float v = 0.f;
                if (k < 48) {
                    int c = k >> 4, r = (k >> 2) & 3, s4 = k & 3;
                    int y = 2 * p + r - 1, xx = 2 * q + s4 - 1;
                    if (((unsigned)y < 128u) && ((unsigned)xx < 128u))
                        v = x[((n * 3 + c) * 128 + y) * 128 + xx];
                }
                hv[e] = __float2bfloat16(v);
            }
            *(bf16x8*)&smem[(row << 7) + d * 16] = *(bf16x8*)hv;
        }
    }
    __syncthreads();

    f32x4 acc[4][4];
    #pragma unroll
    for (int mi = 0; mi < 4; ++mi)
        #pragma unroll
        for (int ni = 0; ni < 4; ++ni) acc[mi][ni] = (f32x4){0.f, 0.f, 0.f, 0.f};

    #pragma unroll
    for (int ks = 0; ks < 2; ++ks) {
        bf16x8 av[4], bv[4];
        #pragma unroll
        for (int mi = 0; mi < 4; ++mi)
            av[mi] = *(const bf16x8*)&smem[fragoff64((wr << 6) + (mi << 4) + (lane & 15), ks, lane)];
        #pragma unroll
        for (int ni = 0; ni < 4; ++ni)
            bv[ni] = *(const bf16x8*)&smem[16384 + fragoff64((wc << 6) + (ni << 4) + (lane & 15), ks, lane)];
        #pragma unroll
        for (int mi = 0; mi < 4; ++mi)
            #pragma unroll
            for (int ni = 0; ni < 4; ++ni)
                acc[mi][ni] = __builtin_amdgcn_mfma_f32_16x16x32_bf16(av[mi], bv[ni], acc[mi][ni], 0, 0, 0);
    }

    int rg = (lane >> 4) << 2;
    #pragma unroll
    for (int mi = 0; mi < 4; ++mi)
        #pragma unroll
        for (int ni = 0; ni < 4; ++ni) {
            int o = (wc << 6) + (ni << 4) + (lane & 15);
            float bias = b1[o];
            #pragma unroll
            for (int j = 0; j < 4; ++j) {
                int rowg = posbase + (wr << 6) + (mi << 4) + rg + j;
                int n = rowg >> 12, p = (rowg >> 6) & 63, q = rowg & 63;
                float v = acc[mi][ni][j] + bias;
                v = v > 0.f ? v : 0.f;
                hb[((n * 66 + p + 1) * 66 + q + 1) * 128 + o] = __float2bfloat16(v);
            }
        }
}

// ---- conv2: hb (padded bf16) -> zb bf16 [32768][128] ----
__global__ __launch_bounds__(256) void k_conv2(
    const __hip_bfloat16* __restrict__ hb, const __hip_bfloat16* __restrict__ w2s,
    const float* __restrict__ b2, __hip_bfloat16* __restrict__ zb)
{
    __shared__ char smem[65536];
    int t = threadIdx.x, lane = t & 63, w = t >> 6;
    int wr = w >> 1, wc = w & 1;
    int posbase = blockIdx.x << 7;              // 256 blocks
    int n = posbase >> 10, prow0 = (posbase >> 5) & 31;

    int aoff[8];
    #pragma unroll
    for (int i = 0; i < 8; ++i) {
        int row = (((w << 3) + i) << 2) + (lane >> 4);
        int slot = lane & 15;
        int p = prow0 + (row >> 5), q = row & 31;
        int csw = (slot ^ (row & 7)) << 3;
        aoff[i] = (((n * 66 + 2 * p) * 66 + 2 * q) << 7) + csw;
    }

    f32x4 acc[4][4];
    #pragma unroll
    for (int mi = 0; mi < 4; ++mi)
        #pragma unroll
        for (int ni = 0; ni < 4; ++ni) acc[mi][ni] = (f32x4){0.f, 0.f, 0.f, 0.f};

    for (int rs = 0; rs < 16; ++rs) {
        __syncthreads();
        int rsoff = (((rs >> 2) * 66 + (rs & 3)) << 7);
        const __hip_bfloat16* wsl = w2s + (rs << 14);
        #pragma unroll
        for (int i = 0; i < 8; ++i) {
            gload16(hb + aoff[i] + rsoff, &smem[((w << 3) + i) << 10]);
            gload16(wsl + ((((w << 3) + i) << 9) + (lane << 3)), &smem[32768 + (((w << 3) + i) << 10)]);
        }
        __syncthreads();
        #pragma unroll
        for (int ks = 0; ks < 4; ++ks) {
            bf16x8 av[4], bv[4];
            #pragma unroll
            for (int mi = 0; mi < 4; ++mi)
                av[mi] = *(const bf16x8*)&smem[fragoff((wr << 6) + (mi << 4) + (lane & 15), ks, lane)];
            #pragma unroll
            for (int ni = 0; ni < 4; ++ni)
                bv[ni] = *(const bf16x8*)&smem[32768 + fragoff((wc << 6) + (ni << 4) + (lane & 15), ks, lane)];
            #pragma unroll
            for (int mi = 0; mi < 4; ++mi)
                #pragma unroll
                for (int ni = 0; ni < 4; ++ni)
                    acc[mi][ni] = __builtin_amdgcn_mfma_f32_16x16x32_bf16(av[mi], bv[ni], acc[mi][ni], 0, 0, 0);
        }
    }

    int rg = (lane >> 4) << 2;
    #pragma unroll
    for (int mi = 0; mi < 4; ++mi)
        #pragma unroll
        for (int ni = 0; ni < 4; ++ni) {
            int o = (wc << 6) + (ni << 4) + (lane & 15);
            float bias = b2[o];
            #pragma unroll
            for (int j = 0; j < 4; ++j) {
                int pos = posbase + (wr << 6) + (mi << 4) + rg + j;
                zb[(pos << 7) + o] = __float2bfloat16(acc[mi][ni][j] + bias);
            }
        }
}

// ---- vq: zb bf16 x Eb bf16 MFMA, fused argmin -> idx ----
__global__ __launch_bounds__(256) void k_vq(
    const __hip_bfloat16* __restrict__ zb, const __hip_bfloat16* __restrict__ Eb,
    const float* __restrict__ s2, int* __restrict__ idxout)
{
    __shared__ char smem[65536];
    int t = threadIdx.x, lane = t & 63, w = t >> 6;
    int wr = w >> 1, wc = w & 1;
    int posbase = blockIdx.x << 7;              // 256 blocks

    #pragma unroll
    for (int i = 0; i < 8; ++i) {
        int row = (((w << 3) + i) << 2) + (lane >> 4);
        int slot = lane & 15;
        int csw = (slot ^ (row & 7)) << 3;
        gload16(zb + (((posbase + row) << 7) + csw), &smem[((w << 3) + i) << 10]);
    }

    float bvv[4][4];
    int   bii[4][4];
    #pragma unroll
    for (int mi = 0; mi < 4; ++mi)
        #pragma unroll
        for (int j = 0; j < 4; ++j) { bvv[mi][j] = 3.4e38f; bii[mi][j] = 0; }

    for (int n0 = 0; n0 < 4; ++n0) {
        __syncthreads();
        const __hip_bfloat16* esl = Eb + (n0 << 14);
        #pragma unroll
        for (int i = 0; i < 8; ++i)
            gload16(esl + ((((w << 3) + i) << 9) + (lane << 3)), &smem[32768 + (((w << 3) + i) << 10)]);
        __syncthreads();

        f32x4 acc[4][4];
        #pragma unroll
        for (int mi = 0; mi < 4; ++mi)
            #pragma unroll
            for (int ni = 0; ni < 4; ++ni) acc[mi][ni] = (f32x4){0.f, 0.f, 0.f, 0.f};

        #pragma unroll
        for (int ks = 0; ks < 4; ++ks) {
            bf16x8 av[4], bv[4];
            #pragma unroll
            for (int mi = 0; mi < 4; ++mi)
                av[mi] = *(const bf16x8*)&smem[fragoff((wr << 6) + (mi << 4) + (lane & 15), ks, lane)];
            #pragma unroll
            for (int ni = 0; ni < 4; ++ni)
                bv[ni] = *(const bf16x8*)&smem[32768 + fragoff((wc << 6) + (ni << 4) + (lane & 15), ks, lane)];
            #pragma unroll
            for (int mi = 0; mi < 4; ++mi)
                #pragma unroll
                for (int ni = 0; ni < 4; ++ni)
                    acc[mi][ni] = __builtin_amdgcn_mfma_f32_16x16x32_bf16(av[mi], bv[ni], acc[mi][ni], 0, 0, 0);
        }

        float s2v[4];
        #pragma unroll
        for (int ni = 0; ni < 4; ++ni)
            s2v[ni] = s2[(n0 << 7) + (wc << 6) + (ni << 4) + (lane & 15)];
        #pragma unroll
        for (int mi = 0; mi < 4; ++mi)
            #pragma unroll
            for (int ni = 0; ni < 4; ++ni) {
                int k = (n0 << 7) + (wc << 6) + (ni << 4) + (lane & 15);
                #pragma unroll
                for (int j = 0; j < 4; ++j) {
                    float sc = s2v[ni] - 2.f * acc[mi][ni][j];
                    if (sc < bvv[mi][j]) { bvv[mi][j] = sc; bii[mi][j] = k; }
                }
            }
    }

    __syncthreads();
    float* redv = (float*)smem;
    int*   redi = (int*)(smem + 1024);
    #pragma unroll
    for (int mi = 0; mi < 4; ++mi)
        #pragma unroll
        for (int j = 0; j < 4; ++j) {
            float v = bvv[mi][j];
            int   ix = bii[mi][j];
            #pragma unroll
            for (int m = 1; m < 16; m <<= 1) {
                float ov = __shfl_xor(v, m, 64);
                int   oi = __shfl_xor(ix, m, 64);
                if (ov < v || (ov == v && oi < ix)) { v = ov; ix = oi; }
            }
            if ((lane & 15) == 0) {
                int row = (wr << 6) + (mi << 4) + ((lane >> 4) << 2) + j;
                redv[row * 2 + wc] = v;
                redi[row * 2 + wc] = ix;
            }
        }
    __syncthreads();
    if (t < 128) {
        float v0 = redv[t * 2], v1 = redv[t * 2 + 1];
        int   i0 = redi[t * 2], i1 = redi[t * 2 + 1];
        int best = (v1 < v0 || (v1 == v0 && i1 < i0)) ? i1 : i0;
        idxout[posbase + t] = best;
    }
}

// ---- scatter: dq bf16 padded [32,34,34,128] <- E[idx] (no-permute reshape) ----
__global__ void k_scatter(const float* __restrict__ E, const int* __restrict__ idx,
                          __hip_bfloat16* __restrict__ dq)
{
    int tid = blockIdx.x * 256 + threadIdx.x;   // 32*34*34*128 = 4,734,976
    int c = tid & 127;
    int rest = tid >> 7;
    int xx = rest % 34;
    int t2 = rest / 34;
    int yy = t2 % 34;
    int n = t2 / 34;
    float v = 0.f;
    if (yy >= 1 && yy <= 32 && xx >= 1 && xx <= 32) {
        int y = yy - 1, x = xx - 1;
        int pos = (y << 5) | x;
        int row = (n << 10) + (c << 3) + (pos >> 7);
        int col = pos & 127;
        v = E[idx[row] * 128 + col];
    }
    dq[tid] = __float2bfloat16(v);
}

// ---- deconv1: dq (padded bf16) -> relu -> g bf16 padded [32,66,66,128] ----
__global__ __launch_bounds__(256) void k_deconv1(
    const __hip_bfloat16* __restrict__ dq, const __hip_bfloat16* __restrict__ w1s,
    const float* __restrict__ b1, __hip_bfloat16* __restrict__ g)
{
    __shared__ char smem[65536];
    int t = threadIdx.x, lane = t & 63, w = t >> 6;
    int wr = w >> 1, wc = w & 1;
    int bid = blockIdx.x;                       // 1024 blocks
    int ag = bid & 7, qe = (bid >> 3) & 1, pe = (bid >> 4) & 1, n = bid >> 5;

    int aoff[8];
    #pragma unroll
    for (int i = 0; i < 8; ++i) {
        int row = (((w << 3) + i) << 2) + (lane >> 4);
        int slot = lane & 15;
        int a = (ag << 2) + (row >> 5), b = row & 31;
        int csw = (slot ^ (row & 7)) << 3;
        aoff[i] = (((n * 34 + (a + pe)) * 34 + (b + qe)) << 7) + csw;
    }

    f32x4 acc[4][4];
    #pragma unroll
    for (int mi = 0; mi < 4; ++mi)
        #pragma unroll
        for (int ni = 0; ni < 4; ++ni) acc[mi][ni] = (f32x4){0.f, 0.f, 0.f, 0.f};

    for (int tu = 0; tu < 4; ++tu) {
        __syncthreads();
        int tt = tu >> 1, u = tu & 1;
        int tapoff = ((tt * 34 + u) << 7);
        const __hip_bfloat16* wsl = w1s + ((((pe << 3) | (qe << 2) | tu)) << 14);
        #pragma unroll
        for (int i = 0; i < 8; ++i) {
            gload16(dq + aoff[i] + tapoff, &smem[((w << 3) + i) << 10]);
            gload16(wsl + ((((w << 3) + i) << 9) + (lane << 3)), &smem[32768 + (((w << 3) + i) << 10)]);
        }
        __syncthreads();
        #pragma unroll
        for (int ks = 0; ks < 4; ++ks) {
            bf16x8 av[4], bv[4];
            #pragma unroll
            for (int mi = 0; mi < 4; ++mi)
                av[mi] = *(const bf16x8*)&smem[fragoff((wr << 6) + (mi << 4) + (lane & 15), ks, lane)];
            #pragma unroll
            for (int ni = 0; ni < 4; ++ni)
                bv[ni] = *(const bf16x8*)&smem[32768 + fragoff((wc << 6) + (ni << 4) + (lane & 15), ks, lane)];
            #pragma unroll
            for (int mi = 0; mi < 4; ++mi)
                #pragma unroll
                for (int ni = 0; ni < 4; ++ni)
                    acc[mi][ni] = __builtin_amdgcn_mfma_f32_16x16x32_bf16(av[mi], bv[ni], acc[mi][ni], 0, 0, 0);
        }
    }

    int rg = (lane >> 4) << 2;
    #pragma unroll
    for (int mi = 0; mi < 4; ++mi)
        #pragma unroll
        for (int ni = 0; ni < 4; ++ni) {
            int o = (wc << 6) + (ni << 4) + (lane & 15);
            float bias = b1[o];
            #pragma unroll
            for (int j = 0; j < 4; ++j) {
                int row = (wr << 6) + (mi << 4) + rg + j;
                int a = (ag << 2) + (row >> 5), b = row & 31;
                int y = 2 * a + pe, xx2 = 2 * b + qe;
                float v = acc[mi][ni][j] + bias;
                v = v > 0.f ? v : 0.f;
                g[((n * 66 + y + 1) * 66 + xx2 + 1) * 128 + o] = __float2bfloat16(v);
            }
        }
}

// ---- deconv2 as MFMA GEMM: g (padded bf16) -> sigmoid -> out NCHW fp32 ----
// Per parity (pe,qe): M=128 rows (2 a x 64 b), K=4 taps x 128 c, N=16 (o pad 3).
__global__ __launch_bounds__(256) void k_deconv2g(
    const __hip_bfloat16* __restrict__ g, const __hip_bfloat16* __restrict__ w2db,
    const float* __restrict__ b2, float* __restrict__ out)
{
    __shared__ char smem[49152];                // A 32KB | B 16KB
    int t = threadIdx.x, lane = t & 63, w = t >> 6;
    int bid = blockIdx.x;                       // 4096 = n(32) tile(32) pq(4)
    int pq = bid & 3, tile = (bid >> 2) & 31, n = bid >> 7;
    int pe = pq >> 1, qe = pq & 1;
    int a0 = tile << 1;

    // stage B once: this parity's 4 taps, [tu][16 o][128 c] pre-swizzled, 16KB
    #pragma unroll
    for (int i = 0; i < 4; ++i)
        gload16(w2db + (pq << 13) + (((w << 2) + i) << 6) * 8 + (lane << 3),
                &smem[32768 + (((w << 2) + i) << 10)]);

    int aoff[8];
    #pragma unroll
    for (int i = 0; i < 8; ++i) {
        int row = (((w << 3) + i) << 2) + (lane >> 4);
        int al = row >> 6, b = row & 63;
        int csw = ((lane & 15) ^ (row & 7)) << 3;
        aoff[i] = (((n * 66 + (a0 + al)) * 66 + b) << 7) + csw;
    }

    f32x4 acc[2];
    acc[0] = (f32x4){0.f, 0.f, 0.f, 0.f};
    acc[1] = (f32x4){0.f, 0.f, 0.f, 0.f};

    for (int tu = 0; tu < 4; ++tu) {
        __syncthreads();
        int tt = tu >> 1, u = tu & 1;
        int tapoff = (((pe + tt) * 66 + (qe + u)) << 7);
        #pragma unroll
        for (int i = 0; i < 8; ++i)
            gload16(g + aoff[i] + tapoff, &smem[((w << 3) + i) << 10]);
        __syncthreads();
        #pragma unroll
        for (int ks = 0; ks < 4; ++ks) {
            bf16x8 av[2], bv;
            #pragma unroll
            for (int mi = 0; mi < 2; ++mi)
                av[mi] = *(const bf16x8*)&smem[fragoff((w << 5) + (mi << 4) + (lane & 15), ks, lane)];
            bv = *(const bf16x8*)&smem[32768 + fragoff((tu << 4) + (lane & 15), ks, lane)];
            #pragma unroll
            for (int mi = 0; mi < 2; ++mi)
                acc[mi] = __builtin_amdgcn_mfma_f32_16x16x32_bf16(av[mi], bv, acc[mi], 0, 0, 0);
        }
    }

    int rg = (lane >> 4) << 2;
    int o = lane & 15;
    if (o < 3) {
        float bias = b2[o];
        #pragma unroll
        for (int mi = 0; mi < 2; ++mi)
            #pragma unroll
            for (int j = 0; j < 4; ++j) {
                int row = (w << 5) + (mi << 4) + rg + j;
                int y = 2 * (a0 + (row >> 6)) + pe;
                int x = 2 * (row & 63) + qe;
                float v = acc[mi][j] + bias;
                out[((n * 3 + o) * 128 + y) * 128 + x] = 1.f / (1.f + expf(-v));
            }
    }
}

extern "C" void kernel_launch(void* const* d_in, const int* in_sizes, int n_in,
                              void* d_out, int out_size, void* d_ws, size_t ws_size,
                              hipStream_t stream) {
    const float* x   = (const float*)d_in[0];
    const float* ew1 = (const float*)d_in[1];
    const float* eb1 = (const float*)d_in[2];
    const float* ew2 = (const float*)d_in[3];
    const float* eb2 = (const float*)d_in[4];
    const float* E   = (const float*)d_in[5];
    const float* dw1 = (const float*)d_in[6];
    const float* db1 = (const float*)d_in[7];
    const float* dw2 = (const float*)d_in[8];
    const float* db2 = (const float*)d_in[9];
    float* out = (float*)d_out;

    char* W = (char*)d_ws;
    __hip_bfloat16* hb   = (__hip_bfloat16*)(W + 0);
    __hip_bfloat16* g    = (__hip_bfloat16*)(W + 0);  // union: hb dead after conv2
    __hip_bfloat16* zb   = (__hip_bfloat16*)(W + 67108864);
    __hip_bfloat16* dq   = (__hip_bfloat16*)(W + 75497472);
    __hip_bfloat16* w2s  = (__hip_bfloat16*)(W + 84967424);
    __hip_bfloat16* w1s  = (__hip_bfloat16*)(W + 85491712);
    __hip_bfloat16* Eb   = (__hip_bfloat16*)(W + 86016000);
    __hip_bfloat16* w2db = (__hip_bfloat16*)(W + 86147072);
    float*          s2   = (float*)(W + 86212608);
    int*            idx  = (int*)(W + 86214656);
    __hip_bfloat16* w1b  = (__hip_bfloat16*)(W + 86345728);

    k_init    <<<6626,  256, 0, stream>>>(ew1, ew2, E, dw1, dw2,
                                          hb, w2s, w1s, Eb, w1b, w2db, s2);
    k_conv1g  <<<1024,  256, 0, stream>>>(x, w1b, eb1, hb);
    k_conv2   <<<256,   256, 0, stream>>>(hb, w2s, eb2, zb);
    k_vq      <<<256,   256, 0, stream>>>(zb, Eb, s2, idx);
    k_scatter <<<18496, 256, 0, stream>>>(E, idx, dq);
    k_deconv1 <<<1024,  256, 0, stream>>>(dq, w1s, db1, g);
    k_deconv2g<<<4096,  256, 0, stream>>>(g, w2db, db2, out);
}

// Round 5
// 119.804 us; speedup vs baseline: 21.4988x; 1.3706x over previous
//
#include <hip/hip_runtime.h>
#include <hip/hip_bf16.h>
#include <math.h>

// ---------------------------------------------------------------------------
// VQ-VAE forward. All five heavy ops are bf16 MFMA implicit GEMMs.
// deconv2 uses a 9-neighbor formulation (all 4 output parities in N).
// VQ fuses the codebook scatter (dq write) into its epilogue.
// ws layout (bytes):
//   0          : hb   bf16 [32][66][66][128] (padded conv1 out)  35,684,352
//                g    bf16 [32][66][66][128] (padded deconv1 out, UNION)
//   67108864   : zb   bf16 [32768][128]                           8,388,608
//   75497472   : dq   bf16 [32][34][34][128] (padded VQ out)      9,469,952
//   84967424   : w2s  bf16 [16 rs][128 o][128 c] pre-swizzled       524,288
//   85491712   : w1s  bf16 [16 m ][128 o][128 c] pre-swizzled       524,288
//   86016000   : Eb   bf16 [512 k][128 c]  pre-swizzled             131,072
//   86147072   : w2db9 bf16 [9 de][16 col][128 c] pre-swizzled       36,864
//   86184192   : s2   f32  [512]                                      2,048
//   86186240   : w1b  bf16 [128 o][64 K] pre-swizzled (conv1)        16,384
// ---------------------------------------------------------------------------

typedef __attribute__((ext_vector_type(8))) short bf16x8;
typedef __attribute__((ext_vector_type(4))) float f32x4;

__device__ __forceinline__ void gload16(const void* g, const void* l) {
    __builtin_amdgcn_global_load_lds(
        (const __attribute__((address_space(1))) void*)g,
        (__attribute__((address_space(3))) void*)l, 16, 0, 0);
}

// byte offset of the 16B fragment (row, k-sub ks) in a swizzled [*][128c] bf16 tile
__device__ __forceinline__ int fragoff(int row, int ks, int lane) {
    return (row << 8) + (((ks << 6) + (lane & 0x30)) ^ ((row & 7) << 4));
}
// same for a [*][64K] tile (128B rows), ks in {0,1}
__device__ __forceinline__ int fragoff64(int row, int ks, int lane) {
    return (row << 7) + (((ks << 6) + (lane & 0x30)) ^ ((row & 7) << 4));
}

// ---- k_init: border fills + all weight/codebook prep in one dispatch ----
__global__ __launch_bounds__(256) void k_init(
    const float* __restrict__ ew1, const float* __restrict__ ew2,
    const float* __restrict__ E,   const float* __restrict__ dw1,
    const float* __restrict__ dw2,
    __hip_bfloat16* __restrict__ hb,  __hip_bfloat16* __restrict__ w2s,
    __hip_bfloat16* __restrict__ w1s, __hip_bfloat16* __restrict__ Eb,
    __hip_bfloat16* __restrict__ w1b, __hip_bfloat16* __restrict__ w2db9,
    __hip_bfloat16* __restrict__ dq,  float* __restrict__ s2)
{
    int bid = blockIdx.x, t = threadIdx.x;
    if (bid < 4160) {                               // hb/g border ring
        int tid = bid * 256 + t;                    // 1,064,960
        const int NROW = 32 * 2 * 66 * 128;
        if (tid < NROW) {
            int c = tid & 127;
            int xx = (tid >> 7) % 66;
            int r2 = tid / (66 * 128);
            int yy = (r2 & 1) * 65;
            int n = r2 >> 1;
            hb[((n * 66 + yy) * 66 + xx) * 128 + c] = __float2bfloat16(0.f);
        } else {
            int t2 = tid - NROW;
            int c = t2 & 127;
            int xs = (t2 >> 7) & 1;
            int yy = ((t2 >> 8) & 63) + 1;
            int n = t2 >> 14;
            hb[((n * 66 + yy) * 66 + xs * 65) * 128 + c] = __float2bfloat16(0.f);
        }
    } else if (bid < 5184) {                        // w2s
        int tid = (bid - 4160) * 256 + t;           // 262144
        int cpos = tid & 127, o = (tid >> 7) & 127, rs = tid >> 14;
        int r = rs >> 2, s = rs & 3;
        int slot = cpos >> 3, e = cpos & 7;
        int csrc = ((slot ^ (o & 7)) << 3) | e;
        w2s[tid] = __float2bfloat16(ew2[((o * 128 + csrc) * 4 + r) * 4 + s]);
    } else if (bid < 6208) {                        // w1s
        int tid = (bid - 5184) * 256 + t;           // 262144
        int cpos = tid & 127, o = (tid >> 7) & 127, m = tid >> 14;
        int pe = (m >> 3) & 1, qe = (m >> 2) & 1, tt = (m >> 1) & 1, u = m & 1;
        int slot = cpos >> 3, e = cpos & 7;
        int csrc = ((slot ^ (o & 7)) << 3) | e;
        w1s[tid] = __float2bfloat16(dw1[((o * 128 + csrc) * 4 + (pe + 2 * tt)) * 4 + (qe + 2 * u)]);
    } else if (bid < 6464) {                        // Eb
        int tid = (bid - 6208) * 256 + t;           // 65536
        int cpos = tid & 127, k = tid >> 7;
        int slot = cpos >> 3, e = cpos & 7;
        int csrc = ((slot ^ (k & 7)) << 3) | e;
        Eb[tid] = __float2bfloat16(E[k * 128 + csrc]);
    } else if (bid < 6496) {                        // w1b (conv1, K pad 48->64)
        int tid = (bid - 6464) * 256 + t;           // 8192
        int o = tid >> 6, cpos = tid & 63;
        int slot = cpos >> 3, e = cpos & 7;
        int k = ((slot ^ (o & 7)) << 3) | e;
        float v = 0.f;
        if (k < 48) {
            int c = k >> 4, r = (k >> 2) & 3, s = k & 3;
            v = ew1[((o * 3 + c) * 4 + r) * 4 + s];
        }
        w1b[tid] = __float2bfloat16(v);
    } else if (bid < 6568) {                        // w2db9 (deconv2 9-neighbor B)
        int tid = (bid - 6496) * 256 + t;           // 18432
        int cpos = tid & 127;
        int col = (tid >> 7) & 15;
        int de = tid >> 11;                         // 0..8
        int o = col & 3, pq = col >> 2;
        int d = de / 3, e_ = de - d * 3;
        int pe = pq >> 1, qe = pq & 1;
        int tt = d - pe, u = e_ - qe;
        float v = 0.f;
        if (o < 3 && tt >= 0 && tt < 2 && u >= 0 && u < 2) {
            int slot = cpos >> 3, el = cpos & 7;
            int csrc = ((slot ^ (col & 7)) << 3) | el;
            v = dw2[((o * 128 + csrc) * 4 + (pe + 2 * tt)) * 4 + (qe + 2 * u)];
        }
        w2db9[tid] = __float2bfloat16(v);
    } else if (bid < 6570) {                        // sumE2
        int k = (bid - 6568) * 256 + t;             // 512
        float a = 0.f;
        const float* e = E + k * 128;
        for (int c = 0; c < 128; ++c) a = fmaf(e[c], e[c], a);
        s2[k] = a;
    } else {                                        // dq border ring
        int tid = (bid - 6570) * 256 + t;           // 540,672
        int n = tid / 16896;
        int rem = tid - n * 16896;
        int c = rem & 127;
        int pp = rem >> 7;                          // 0..131
        int yy, xx;
        if (pp < 68) { yy = (pp >= 34) ? 33 : 0; xx = pp % 34; }
        else { int q = pp - 68; yy = 1 + (q >> 1); xx = (q & 1) * 33; }
        dq[((n * 34 + yy) * 34 + xx) * 128 + c] = __float2bfloat16(0.f);
    }
}

// ---- conv1 as MFMA implicit GEMM with fused im2col staging ----
__global__ __launch_bounds__(256) void k_conv1g(
    const float* __restrict__ x, const __hip_bfloat16* __restrict__ w1b,
    const float* __restrict__ b1, __hip_bfloat16* __restrict__ hb)
{
    __shared__ char smem[32768];                    // A 16KB | B 16KB
    int t = threadIdx.x, lane = t & 63, w = t >> 6;
    int wr = w >> 1, wc = w & 1;
    int bid0 = blockIdx.x;                          // 1024
    int bid = ((bid0 & 7) << 7) | (bid0 >> 3);      // XCD swizzle
    int posbase = bid << 7;

    #pragma unroll
    for (int i = 0; i < 4; ++i)
        gload16(w1b + ((w * 4 + i) * 512 + lane * 8), &smem[16384 + ((w * 4 + i) << 10)]);

    {
        int row = t >> 1, half = t & 1;
        int rowg = posbase + row;
        int n = rowg >> 12, p = (rowg >> 6) & 63, q = rowg & 63;
        #pragma unroll
        for (int j = 0; j < 4; ++j) {
            int d = half * 4 + j;
            int sct = d ^ (row & 7);
            __hip_bfloat16 hv[8];
            #pragma unroll
            for (int e = 0; e < 8; ++e) {
                int k = sct * 8 + e;
                float v = 0.f;
                if (k < 48) {
                    int c = k >> 4, r = (k >> 2) & 3, s4 = k & 3;
                    int y = 2 * p + r - 1, xx = 2 * q + s4 - 1;
                    if (((unsigned)y < 128u) && ((unsigned)xx < 128u))
                        v = x[((n * 3 + c) * 128 + y) * 128 + xx];
                }
                hv[e] = __float2bfloat16(v);
            }
            *(bf16x8*)&smem[(row << 7) + d * 16] = *(bf16x8*)hv;
        }
    }
    __syncthreads();

    f32x4 acc[4][4];
    #pragma unroll
    for (int mi = 0; mi < 4; ++mi)
        #pragma unroll
        for (int ni = 0; ni < 4; ++ni) acc[mi][ni] = (f32x4){0.f, 0.f, 0.f, 0.f};

    #pragma unroll
    for (int ks = 0; ks < 2; ++ks) {
        bf16x8 av[4], bv[4];
        #pragma unroll
        for (int mi = 0; mi < 4; ++mi)
            av[mi] = *(const bf16x8*)&smem[fragoff64((wr << 6) + (mi << 4) + (lane & 15), ks, lane)];
        #pragma unroll
        for (int ni = 0; ni < 4; ++ni)
            bv[ni] = *(const bf16x8*)&smem[16384 + fragoff64((wc << 6) + (ni << 4) + (lane & 15), ks, lane)];
        #pragma unroll
        for (int mi = 0; mi < 4; ++mi)
            #pragma unroll
            for (int ni = 0; ni < 4; ++ni)
                acc[mi][ni] = __builtin_amdgcn_mfma_f32_16x16x32_bf16(av[mi], bv[ni], acc[mi][ni], 0, 0, 0);
    }

    int rg = (lane >> 4) << 2;
    #pragma unroll
    for (int mi = 0; mi < 4; ++mi)
        #pragma unroll
        for (int ni = 0; ni < 4; ++ni) {
            int o = (wc << 6) + (ni << 4) + (lane & 15);
            float bias = b1[o];
            #pragma unroll
            for (int j = 0; j < 4; ++j) {
                int rowg = posbase + (wr << 6) + (mi << 4) + rg + j;
                int n = rowg >> 12, p = (rowg >> 6) & 63, q = rowg & 63;
                float v = acc[mi][ni][j] + bias;
                v = v > 0.f ? v : 0.f;
                hb[((n * 66 + p + 1) * 66 + q + 1) * 128 + o] = __float2bfloat16(v);
            }
        }
}

// ---- conv2: hb (padded bf16) -> zb bf16.  M=64 tiles, grid 512, LDS 48KB ----
__global__ __launch_bounds__(256) void k_conv2(
    const __hip_bfloat16* __restrict__ hb, const __hip_bfloat16* __restrict__ w2s,
    const float* __restrict__ b2, __hip_bfloat16* __restrict__ zb)
{
    __shared__ char smem[49152];                // A 16KB | B 32KB
    int t = threadIdx.x, lane = t & 63, w = t >> 6;
    int bid0 = blockIdx.x;                      // 512
    int bid = ((bid0 & 7) << 6) | (bid0 >> 3);  // XCD swizzle
    int posbase = bid << 6;
    int n = posbase >> 10, p0 = (posbase >> 5) & 31;

    int aoff[4];
    #pragma unroll
    for (int i = 0; i < 4; ++i) {
        int row = (((w << 2) + i) << 2) + (lane >> 4);
        int slot = lane & 15;
        int p = p0 + (row >> 5), q = row & 31;
        int csw = (slot ^ (row & 7)) << 3;
        aoff[i] = (((n * 66 + 2 * p) * 66 + 2 * q) << 7) + csw;
    }

    f32x4 acc[4][2];
    #pragma unroll
    for (int mi = 0; mi < 4; ++mi)
        #pragma unroll
        for (int ni = 0; ni < 2; ++ni) acc[mi][ni] = (f32x4){0.f, 0.f, 0.f, 0.f};

    for (int rs = 0; rs < 16; ++rs) {
        __syncthreads();
        int rsoff = (((rs >> 2) * 66 + (rs & 3)) << 7);
        const __hip_bfloat16* wsl = w2s + (rs << 14);
        #pragma unroll
        for (int i = 0; i < 4; ++i)
            gload16(hb + aoff[i] + rsoff, &smem[((w << 2) + i) << 10]);
        #pragma unroll
        for (int i = 0; i < 8; ++i)
            gload16(wsl + ((((w << 3) + i) << 9) + (lane << 3)), &smem[16384 + (((w << 3) + i) << 10)]);
        __syncthreads();
        #pragma unroll
        for (int ks = 0; ks < 4; ++ks) {
            bf16x8 av[4], bv[2];
            #pragma unroll
            for (int mi = 0; mi < 4; ++mi)
                av[mi] = *(const bf16x8*)&smem[fragoff((mi << 4) + (lane & 15), ks, lane)];
            #pragma unroll
            for (int ni = 0; ni < 2; ++ni)
                bv[ni] = *(const bf16x8*)&smem[16384 + fragoff((w << 5) + (ni << 4) + (lane & 15), ks, lane)];
            #pragma unroll
            for (int mi = 0; mi < 4; ++mi)
                #pragma unroll
                for (int ni = 0; ni < 2; ++ni)
                    acc[mi][ni] = __builtin_amdgcn_mfma_f32_16x16x32_bf16(av[mi], bv[ni], acc[mi][ni], 0, 0, 0);
        }
    }

    int rg = (lane >> 4) << 2;
    #pragma unroll
    for (int mi = 0; mi < 4; ++mi)
        #pragma unroll
        for (int ni = 0; ni < 2; ++ni) {
            int o = (w << 5) + (ni << 4) + (lane & 15);
            float bias = b2[o];
            #pragma unroll
            for (int j = 0; j < 4; ++j) {
                int pos = posbase + (mi << 4) + rg + j;
                zb[(pos << 7) + o] = __float2bfloat16(acc[mi][ni][j] + bias);
            }
        }
}

// ---- vq: MFMA argmin over codebook, FUSED dq scatter-write epilogue ----
__global__ __launch_bounds__(256) void k_vq(
    const __hip_bfloat16* __restrict__ zb, const __hip_bfloat16* __restrict__ Eb,
    const float* __restrict__ s2, const float* __restrict__ E,
    __hip_bfloat16* __restrict__ dq)
{
    __shared__ char smem[65536];
    int t = threadIdx.x, lane = t & 63, w = t >> 6;
    int wr = w >> 1, wc = w & 1;
    int posbase = blockIdx.x << 7;              // 256 blocks

    #pragma unroll
    for (int i = 0; i < 8; ++i) {
        int row = (((w << 3) + i) << 2) + (lane >> 4);
        int slot = lane & 15;
        int csw = (slot ^ (row & 7)) << 3;
        gload16(zb + (((posbase + row) << 7) + csw), &smem[((w << 3) + i) << 10]);
    }

    float bvv[4][4];
    int   bii[4][4];
    #pragma unroll
    for (int mi = 0; mi < 4; ++mi)
        #pragma unroll
        for (int j = 0; j < 4; ++j) { bvv[mi][j] = 3.4e38f; bii[mi][j] = 0; }

    for (int n0 = 0; n0 < 4; ++n0) {
        __syncthreads();
        const __hip_bfloat16* esl = Eb + (n0 << 14);
        #pragma unroll
        for (int i = 0; i < 8; ++i)
            gload16(esl + ((((w << 3) + i) << 9) + (lane << 3)), &smem[32768 + (((w << 3) + i) << 10)]);
        __syncthreads();

        f32x4 acc[4][4];
        #pragma unroll
        for (int mi = 0; mi < 4; ++mi)
            #pragma unroll
            for (int ni = 0; ni < 4; ++ni) acc[mi][ni] = (f32x4){0.f, 0.f, 0.f, 0.f};

        #pragma unroll
        for (int ks = 0; ks < 4; ++ks) {
            bf16x8 av[4], bv[4];
            #pragma unroll
            for (int mi = 0; mi < 4; ++mi)
                av[mi] = *(const bf16x8*)&smem[fragoff((wr << 6) + (mi << 4) + (lane & 15), ks, lane)];
            #pragma unroll
            for (int ni = 0; ni < 4; ++ni)
                bv[ni] = *(const bf16x8*)&smem[32768 + fragoff((wc << 6) + (ni << 4) + (lane & 15), ks, lane)];
            #pragma unroll
            for (int mi = 0; mi < 4; ++mi)
                #pragma unroll
                for (int ni = 0; ni < 4; ++ni)
                    acc[mi][ni] = __builtin_amdgcn_mfma_f32_16x16x32_bf16(av[mi], bv[ni], acc[mi][ni], 0, 0, 0);
        }

        float s2v[4];
        #pragma unroll
        for (int ni = 0; ni < 4; ++ni)
            s2v[ni] = s2[(n0 << 7) + (wc << 6) + (ni << 4) + (lane & 15)];
        #pragma unroll
        for (int mi = 0; mi < 4; ++mi)
            #pragma unroll
            for (int ni = 0; ni < 4; ++ni) {
                int k = (n0 << 7) + (wc << 6) + (ni << 4) + (lane & 15);
                #pragma unroll
                for (int j = 0; j < 4; ++j) {
                    float sc = s2v[ni] - 2.f * acc[mi][ni][j];
                    if (sc < bvv[mi][j]) { bvv[mi][j] = sc; bii[mi][j] = k; }
                }
            }
    }

    __syncthreads();
    float* redv  = (float*)smem;
    int*   redi  = (int*)(smem + 1024);
    int*   idx_l = (int*)(smem + 32768);
    #pragma unroll
    for (int mi = 0; mi < 4; ++mi)
        #pragma unroll
        for (int j = 0; j < 4; ++j) {
            float v = bvv[mi][j];
            int   ix = bii[mi][j];
            #pragma unroll
            for (int m = 1; m < 16; m <<= 1) {
                float ov = __shfl_xor(v, m, 64);
                int   oi = __shfl_xor(ix, m, 64);
                if (ov < v || (ov == v && oi < ix)) { v = ov; ix = oi; }
            }
            if ((lane & 15) == 0) {
                int row = (wr << 6) + (mi << 4) + ((lane >> 4) << 2) + j;
                redv[row * 2 + wc] = v;
                redi[row * 2 + wc] = ix;
            }
        }
    __syncthreads();
    if (t < 128) {
        float v0 = redv[t * 2], v1 = redv[t * 2 + 1];
        int   i0 = redi[t * 2], i1 = redi[t * 2 + 1];
        idx_l[t] = (v1 < v0 || (v1 == v0 && i1 < i0)) ? i1 : i0;
    }
    __syncthreads();

    // stage selected E rows (f32 -> bf16) into smem[0..32768): [128 j][128 lo]
    {
        int j = t >> 1, half = t & 1;
        const float* er = E + idx_l[j] * 128 + half * 64;
        unsigned short* dstl = (unsigned short*)smem + j * 128 + half * 64;
        #pragma unroll
        for (int q4 = 0; q4 < 16; ++q4) {
            float4 v = *(const float4*)(er + q4 * 4);
            union { __hip_bfloat16 h[4]; unsigned long long u; } pk;
            pk.h[0] = __float2bfloat16(v.x); pk.h[1] = __float2bfloat16(v.y);
            pk.h[2] = __float2bfloat16(v.z); pk.h[3] = __float2bfloat16(v.w);
            *(unsigned long long*)(dstl + q4 * 4) = pk.u;
        }
    }
    __syncthreads();

    // write dq: this block owns channels [cb, cb+16) x all 1024 positions of n
    int n = posbase >> 10;
    int cb = (posbase >> 3) & 127;
    const unsigned short* eb = (const unsigned short*)smem;
    #pragma unroll
    for (int k2 = 0; k2 < 4; ++k2) {
        int sp = k2 * 256 + t;
        int hi = sp >> 7, lo = sp & 127;
        int y = hi * 4 + (lo >> 5), x = lo & 31;
        unsigned short vals[16];
        #pragma unroll
        for (int ci = 0; ci < 16; ++ci)
            vals[ci] = eb[((((ci << 3) | hi)) << 7) + lo];
        __hip_bfloat16* dst = dq + ((n * 34 + y + 1) * 34 + (x + 1)) * 128 + cb;
        *(bf16x8*)dst = *(bf16x8*)&vals[0];
        *(bf16x8*)(dst + 8) = *(bf16x8*)&vals[8];
    }
}

// ---- deconv1: dq (padded bf16) -> relu -> g bf16 padded [32,66,66,128] ----
__global__ __launch_bounds__(256) void k_deconv1(
    const __hip_bfloat16* __restrict__ dq, const __hip_bfloat16* __restrict__ w1s,
    const float* __restrict__ b1, __hip_bfloat16* __restrict__ g)
{
    __shared__ char smem[65536];
    int t = threadIdx.x, lane = t & 63, w = t >> 6;
    int wr = w >> 1, wc = w & 1;
    int bid0 = blockIdx.x;                      // 1024
    int bid = ((bid0 & 7) << 7) | (bid0 >> 3);  // XCD swizzle
    int ag = bid & 7, qe = (bid >> 3) & 1, pe = (bid >> 4) & 1, n = bid >> 5;

    int aoff[8];
    #pragma unroll
    for (int i = 0; i < 8; ++i) {
        int row = (((w << 3) + i) << 2) + (lane >> 4);
        int slot = lane & 15;
        int a = (ag << 2) + (row >> 5), b = row & 31;
        int csw = (slot ^ (row & 7)) << 3;
        aoff[i] = (((n * 34 + (a + pe)) * 34 + (b + qe)) << 7) + csw;
    }

    f32x4 acc[4][4];
    #pragma unroll
    for (int mi = 0; mi < 4; ++mi)
        #pragma unroll
        for (int ni = 0; ni < 4; ++ni) acc[mi][ni] = (f32x4){0.f, 0.f, 0.f, 0.f};

    for (int tu = 0; tu < 4; ++tu) {
        __syncthreads();
        int tt = tu >> 1, u = tu & 1;
        int tapoff = ((tt * 34 + u) << 7);
        const __hip_bfloat16* wsl = w1s + ((((pe << 3) | (qe << 2) | tu)) << 14);
        #pragma unroll
        for (int i = 0; i < 8; ++i) {
            gload16(dq + aoff[i] + tapoff, &smem[((w << 3) + i) << 10]);
            gload16(wsl + ((((w << 3) + i) << 9) + (lane << 3)), &smem[32768 + (((w << 3) + i) << 10)]);
        }
        __syncthreads();
        #pragma unroll
        for (int ks = 0; ks < 4; ++ks) {
            bf16x8 av[4], bv[4];
            #pragma unroll
            for (int mi = 0; mi < 4; ++mi)
                av[mi] = *(const bf16x8*)&smem[fragoff((wr << 6) + (mi << 4) + (lane & 15), ks, lane)];
            #pragma unroll
            for (int ni = 0; ni < 4; ++ni)
                bv[ni] = *(const bf16x8*)&smem[32768 + fragoff((wc << 6) + (ni << 4) + (lane & 15), ks, lane)];
            #pragma unroll
            for (int mi = 0; mi < 4; ++mi)
                #pragma unroll
                for (int ni = 0; ni < 4; ++ni)
                    acc[mi][ni] = __builtin_amdgcn_mfma_f32_16x16x32_bf16(av[mi], bv[ni], acc[mi][ni], 0, 0, 0);
        }
    }

    int rg = (lane >> 4) << 2;
    #pragma unroll
    for (int mi = 0; mi < 4; ++mi)
        #pragma unroll
        for (int ni = 0; ni < 4; ++ni) {
            int o = (wc << 6) + (ni << 4) + (lane & 15);
            float bias = b1[o];
            #pragma unroll
            for (int j = 0; j < 4; ++j) {
                int row = (wr << 6) + (mi << 4) + rg + j;
                int a = (ag << 2) + (row >> 5), b = row & 31;
                int y = 2 * a + pe, xx2 = 2 * b + qe;
                float v = acc[mi][ni][j] + bias;
                v = v > 0.f ? v : 0.f;
                g[((n * 66 + y + 1) * 66 + xx2 + 1) * 128 + o] = __float2bfloat16(v);
            }
        }
}

// ---- deconv2, 9-neighbor form: all 4 parities in N.  grid 1024, LDS 36KB ----
// M=128 rows (2a x 64b), K=9 steps x 128c, N=16 (col = pq*4+o, o<3 valid).
__global__ __launch_bounds__(256) void k_deconv2g(
    const __hip_bfloat16* __restrict__ g, const __hip_bfloat16* __restrict__ w2db9,
    const float* __restrict__ b2, float* __restrict__ out)
{
    __shared__ char smem[36864];                // A 32KB | B 4KB
    int t = threadIdx.x, lane = t & 63, w = t >> 6;
    int bid0 = blockIdx.x;                      // 1024
    int bid = ((bid0 & 7) << 7) | (bid0 >> 3);  // XCD swizzle
    int atile = bid & 31, n = bid >> 5;
    int a0 = atile << 1;

    int aoff[8];
    #pragma unroll
    for (int i = 0; i < 8; ++i) {
        int row = (((w << 3) + i) << 2) + (lane >> 4);
        int al = row >> 6, b = row & 63;
        int csw = ((lane & 15) ^ (row & 7)) << 3;
        aoff[i] = (((n * 66 + (a0 + al)) * 66 + b) << 7) + csw;
    }

    f32x4 acc[2];
    acc[0] = (f32x4){0.f, 0.f, 0.f, 0.f};
    acc[1] = (f32x4){0.f, 0.f, 0.f, 0.f};

    for (int de = 0; de < 9; ++de) {
        __syncthreads();
        int dy = de / 3, dx = de - dy * 3;
        int tapoff = ((dy * 66 + dx) << 7);
        #pragma unroll
        for (int i = 0; i < 8; ++i)
            gload16(g + aoff[i] + tapoff, &smem[((w << 3) + i) << 10]);
        gload16(w2db9 + (de << 11) + (w << 9) + (lane << 3), &smem[32768 + (w << 10)]);
        __syncthreads();
        #pragma unroll
        for (int ks = 0; ks < 4; ++ks) {
            bf16x8 av[2], bv;
            #pragma unroll
            for (int mi = 0; mi < 2; ++mi)
                av[mi] = *(const bf16x8*)&smem[fragoff((w << 5) + (mi << 4) + (lane & 15), ks, lane)];
            bv = *(const bf16x8*)&smem[32768 + fragoff(lane & 15, ks, lane)];
            #pragma unroll
            for (int mi = 0; mi < 2; ++mi)
                acc[mi] = __builtin_amdgcn_mfma_f32_16x16x32_bf16(av[mi], bv, acc[mi], 0, 0, 0);
        }
    }

    int rg = (lane >> 4) << 2;
    int col = lane & 15, o = col & 3, pq = col >> 2;
    if (o < 3) {
        int pe = pq >> 1, qe = pq & 1;
        float bias = b2[o];
        #pragma unroll
        for (int mi = 0; mi < 2; ++mi)
            #pragma unroll
            for (int j = 0; j < 4; ++j) {
                int row = (w << 5) + (mi << 4) + rg + j;
                int y = 2 * (a0 + (row >> 6)) + pe;
                int x = 2 * (row & 63) + qe;
                float v = acc[mi][j] + bias;
                out[((n * 3 + o) * 128 + y) * 128 + x] = 1.f / (1.f + expf(-v));
            }
    }
}

extern "C" void kernel_launch(void* const* d_in, const int* in_sizes, int n_in,
                              void* d_out, int out_size, void* d_ws, size_t ws_size,
                              hipStream_t stream) {
    const float* x   = (const float*)d_in[0];
    const float* ew1 = (const float*)d_in[1];
    const float* eb1 = (const float*)d_in[2];
    const float* ew2 = (const float*)d_in[3];
    const float* eb2 = (const float*)d_in[4];
    const float* E   = (const float*)d_in[5];
    const float* dw1 = (const float*)d_in[6];
    const float* db1 = (const float*)d_in[7];
    const float* dw2 = (const float*)d_in[8];
    const float* db2 = (const float*)d_in[9];
    float* out = (float*)d_out;

    char* W = (char*)d_ws;
    __hip_bfloat16* hb    = (__hip_bfloat16*)(W + 0);
    __hip_bfloat16* g     = (__hip_bfloat16*)(W + 0);  // union: hb dead after conv2
    __hip_bfloat16* zb    = (__hip_bfloat16*)(W + 67108864);
    __hip_bfloat16* dq    = (__hip_bfloat16*)(W + 75497472);
    __hip_bfloat16* w2s   = (__hip_bfloat16*)(W + 84967424);
    __hip_bfloat16* w1s   = (__hip_bfloat16*)(W + 85491712);
    __hip_bfloat16* Eb    = (__hip_bfloat16*)(W + 86016000);
    __hip_bfloat16* w2db9 = (__hip_bfloat16*)(W + 86147072);
    float*          s2    = (float*)(W + 86184192);
    __hip_bfloat16* w1b   = (__hip_bfloat16*)(W + 86186240);

    k_init    <<<8682,  256, 0, stream>>>(ew1, ew2, E, dw1, dw2,
                                          hb, w2s, w1s, Eb, w1b, w2db9, dq, s2);
    k_conv1g  <<<1024,  256, 0, stream>>>(x, w1b, eb1, hb);
    k_conv2   <<<512,   256, 0, stream>>>(hb, w2s, eb2, zb);
    k_vq      <<<256,   256, 0, stream>>>(zb, Eb, s2, E, dq);
    k_deconv1 <<<1024,  256, 0, stream>>>(dq, w1s, db1, g);
    k_deconv2g<<<1024,  256, 0, stream>>>(g, w2db9, db2, out);
}

// Round 6
// 119.666 us; speedup vs baseline: 21.5236x; 1.0012x over previous
//
#include <hip/hip_runtime.h>
#include <hip/hip_bf16.h>
#include <math.h>

// ---------------------------------------------------------------------------
// VQ-VAE forward. conv1 / conv2+vq / deconv1 / deconv2 are bf16 MFMA implicit
// GEMMs (global_load_lds staging with source-address swizzle, XOR-swizzled
// LDS reads). VQ (argmin + codebook scatter) is fused into conv2's epilogue.
// ws layout (bytes):
//   0          : hb    bf16 [32][66][66][128] (padded conv1 out) 35,684,352
//                g     bf16 [32][66][66][128] (padded deconv1 out, UNION)
//   75497472   : dq    bf16 [32][34][34][128] (padded VQ out)     9,469,952
//   84967424   : w2p   bf16 [16 rs][128 o][128 c] PLAIN             524,288
//   85491712   : w1p   bf16 [16 m ][128 o][128 c] PLAIN             524,288
//   86016000   : Ep    bf16 [512 k][128 c]  PLAIN                   131,072
//   86147072   : w2db9 bf16 [9 de][16 col][128 c] pre-swizzled       36,864
//   86184192   : s2    f32  [512]                                     2,048
//   86186240   : w1b   bf16 [128 o][64 K] pre-swizzled (conv1)       16,384
// ---------------------------------------------------------------------------

typedef __attribute__((ext_vector_type(8))) short bf16x8;
typedef __attribute__((ext_vector_type(4))) float f32x4;

__device__ __forceinline__ void gload16(const void* g, const void* l) {
    __builtin_amdgcn_global_load_lds(
        (const __attribute__((address_space(1))) void*)g,
        (__attribute__((address_space(3))) void*)l, 16, 0, 0);
}

// byte offset of the 16B fragment (row, ks) in a swizzled [*][128c] bf16 tile (256B rows)
__device__ __forceinline__ int fragoff(int row, int ks, int lane) {
    return (row << 8) + (((ks << 6) + (lane & 0x30)) ^ ((row & 7) << 4));
}
// same for a [*][64c] tile (128B rows), ks in {0,1}
__device__ __forceinline__ int fragoff64(int row, int ks, int lane) {
    return (row << 7) + (((ks << 6) + (lane & 0x30)) ^ ((row & 7) << 4));
}

// ---- k_init: border fills + all weight/codebook prep in one dispatch ----
__global__ __launch_bounds__(256) void k_init(
    const float* __restrict__ ew1, const float* __restrict__ ew2,
    const float* __restrict__ E,   const float* __restrict__ dw1,
    const float* __restrict__ dw2,
    __hip_bfloat16* __restrict__ hb,  __hip_bfloat16* __restrict__ w2p,
    __hip_bfloat16* __restrict__ w1p, __hip_bfloat16* __restrict__ Ep,
    __hip_bfloat16* __restrict__ w1b, __hip_bfloat16* __restrict__ w2db9,
    __hip_bfloat16* __restrict__ dq,  float* __restrict__ s2)
{
    int bid = blockIdx.x, t = threadIdx.x;
    if (bid < 4160) {                               // hb/g border ring
        int tid = bid * 256 + t;                    // 1,064,960
        const int NROW = 32 * 2 * 66 * 128;
        if (tid < NROW) {
            int c = tid & 127;
            int xx = (tid >> 7) % 66;
            int r2 = tid / (66 * 128);
            int yy = (r2 & 1) * 65;
            int n = r2 >> 1;
            hb[((n * 66 + yy) * 66 + xx) * 128 + c] = __float2bfloat16(0.f);
        } else {
            int t2 = tid - NROW;
            int c = t2 & 127;
            int xs = (t2 >> 7) & 1;
            int yy = ((t2 >> 8) & 63) + 1;
            int n = t2 >> 14;
            hb[((n * 66 + yy) * 66 + xs * 65) * 128 + c] = __float2bfloat16(0.f);
        }
    } else if (bid < 5184) {                        // w2p plain [rs][o][c]
        int tid = (bid - 4160) * 256 + t;           // 262144
        int c = tid & 127, o = (tid >> 7) & 127, rs = tid >> 14;
        int r = rs >> 2, s = rs & 3;
        w2p[tid] = __float2bfloat16(ew2[((o * 128 + c) * 4 + r) * 4 + s]);
    } else if (bid < 6208) {                        // w1p plain [m][o][c]
        int tid = (bid - 5184) * 256 + t;           // 262144
        int c = tid & 127, o = (tid >> 7) & 127, m = tid >> 14;
        int pe = (m >> 3) & 1, qe = (m >> 2) & 1, tt = (m >> 1) & 1, u = m & 1;
        w1p[tid] = __float2bfloat16(dw1[((o * 128 + c) * 4 + (pe + 2 * tt)) * 4 + (qe + 2 * u)]);
    } else if (bid < 6464) {                        // Ep plain [k][c]
        int tid = (bid - 6208) * 256 + t;           // 65536
        Ep[tid] = __float2bfloat16(E[tid]);
    } else if (bid < 6496) {                        // w1b (conv1, pre-swizzled, K pad 48->64)
        int tid = (bid - 6464) * 256 + t;           // 8192
        int o = tid >> 6, cpos = tid & 63;
        int slot = cpos >> 3, e = cpos & 7;
        int k = ((slot ^ (o & 7)) << 3) | e;
        float v = 0.f;
        if (k < 48) {
            int c = k >> 4, r = (k >> 2) & 3, s = k & 3;
            v = ew1[((o * 3 + c) * 4 + r) * 4 + s];
        }
        w1b[tid] = __float2bfloat16(v);
    } else if (bid < 6568) {                        // w2db9 (deconv2 9-neighbor B, pre-swizzled)
        int tid = (bid - 6496) * 256 + t;           // 18432
        int cpos = tid & 127;
        int col = (tid >> 7) & 15;
        int de = tid >> 11;                         // 0..8
        int o = col & 3, pq = col >> 2;
        int d = de / 3, e_ = de - d * 3;
        int pe = pq >> 1, qe = pq & 1;
        int tt = d - pe, u = e_ - qe;
        float v = 0.f;
        if (o < 3 && tt >= 0 && tt < 2 && u >= 0 && u < 2) {
            int slot = cpos >> 3, el = cpos & 7;
            int csrc = ((slot ^ (col & 7)) << 3) | el;
            v = dw2[((o * 128 + csrc) * 4 + (pe + 2 * tt)) * 4 + (qe + 2 * u)];
        }
        w2db9[tid] = __float2bfloat16(v);
    } else if (bid < 6570) {                        // sumE2
        int k = (bid - 6568) * 256 + t;             // 512
        float a = 0.f;
        const float* e = E + k * 128;
        for (int c = 0; c < 128; ++c) a = fmaf(e[c], e[c], a);
        s2[k] = a;
    } else {                                        // dq border ring
        int tid = (bid - 6570) * 256 + t;           // 540,672  (2112 blocks)
        int n = tid / 16896;
        int rem = tid - n * 16896;
        int c = rem & 127;
        int pp = rem >> 7;                          // 0..131
        int yy, xx;
        if (pp < 68) { yy = (pp >= 34) ? 33 : 0; xx = pp % 34; }
        else { int q = pp - 68; yy = 1 + (q >> 1); xx = (q & 1) * 33; }
        dq[((n * 34 + yy) * 34 + xx) * 128 + c] = __float2bfloat16(0.f);
    }
}

// ---- conv1 as MFMA implicit GEMM with fused im2col staging (unchanged core) ----
__global__ __launch_bounds__(256) void k_conv1g(
    const float* __restrict__ x, const __hip_bfloat16* __restrict__ w1b,
    const float* __restrict__ b1, __hip_bfloat16* __restrict__ hb)
{
    __shared__ char smem[32768];                    // A 16KB | B 16KB
    int t = threadIdx.x, lane = t & 63, w = t >> 6;
    int wr = w >> 1, wc = w & 1;
    int bid0 = blockIdx.x;                          // 1024
    int bid = ((bid0 & 7) << 7) | (bid0 >> 3);      // XCD swizzle
    int posbase = bid << 7;

    #pragma unroll
    for (int i = 0; i < 4; ++i)
        gload16(w1b + ((w * 4 + i) * 512 + lane * 8), &smem[16384 + ((w * 4 + i) << 10)]);

    {
        int row = t >> 1, half = t & 1;
        int rowg = posbase + row;
        int n = rowg >> 12, p = (rowg >> 6) & 63, q = rowg & 63;
        #pragma unroll
        for (int j = 0; j < 4; ++j) {
            int d = half * 4 + j;
            int sct = d ^ (row & 7);
            __hip_bfloat16 hv[8];
            #pragma unroll
            for (int e = 0; e < 8; ++e) {
                int k = sct * 8 + e;
                float v = 0.f;
                if (k < 48) {
                    int c = k >> 4, r = (k >> 2) & 3, s4 = k & 3;
                    int y = 2 * p + r - 1, xx = 2 * q + s4 - 1;
                    if (((unsigned)y < 128u) && ((unsigned)xx < 128u))
                        v = x[((n * 3 + c) * 128 + y) * 128 + xx];
                }
                hv[e] = __float2bfloat16(v);
            }
            *(bf16x8*)&smem[(row << 7) + d * 16] = *(bf16x8*)hv;
        }
    }
    __syncthreads();

    f32x4 acc[4][4];
    #pragma unroll
    for (int mi = 0; mi < 4; ++mi)
        #pragma unroll
        for (int ni = 0; ni < 4; ++ni) acc[mi][ni] = (f32x4){0.f, 0.f, 0.f, 0.f};

    #pragma unroll
    for (int ks = 0; ks < 2; ++ks) {
        bf16x8 av[4], bv[4];
        #pragma unroll
        for (int mi = 0; mi < 4; ++mi)
            av[mi] = *(const bf16x8*)&smem[fragoff64((wr << 6) + (mi << 4) + (lane & 15), ks, lane)];
        #pragma unroll
        for (int ni = 0; ni < 4; ++ni)
            bv[ni] = *(const bf16x8*)&smem[16384 + fragoff64((wc << 6) + (ni << 4) + (lane & 15), ks, lane)];
        #pragma unroll
        for (int mi = 0; mi < 4; ++mi)
            #pragma unroll
            for (int ni = 0; ni < 4; ++ni)
                acc[mi][ni] = __builtin_amdgcn_mfma_f32_16x16x32_bf16(av[mi], bv[ni], acc[mi][ni], 0, 0, 0);
    }

    int rg = (lane >> 4) << 2;
    #pragma unroll
    for (int mi = 0; mi < 4; ++mi)
        #pragma unroll
        for (int ni = 0; ni < 4; ++ni) {
            int o = (wc << 6) + (ni << 4) + (lane & 15);
            float bias = b1[o];
            #pragma unroll
            for (int j = 0; j < 4; ++j) {
                int rowg = posbase + (wr << 6) + (mi << 4) + rg + j;
                int n = rowg >> 12, p = (rowg >> 6) & 63, q = rowg & 63;
                float v = acc[mi][ni][j] + bias;
                v = v > 0.f ? v : 0.f;
                hb[((n * 66 + p + 1) * 66 + q + 1) * 128 + o] = __float2bfloat16(v);
            }
        }
}

// ---- conv2 + VQ fused: hb -> z (in LDS) -> argmin over E -> dq scatter ----
// conv: M=64 positions, N=128 o, K = 16 rs x 2 ch (BK=64). LDS 32KB.
__global__ __launch_bounds__(256) void k_conv2vq(
    const __hip_bfloat16* __restrict__ hb, const __hip_bfloat16* __restrict__ w2p,
    const float* __restrict__ b2, const __hip_bfloat16* __restrict__ Ep,
    const float* __restrict__ s2, __hip_bfloat16* __restrict__ dq)
{
    __shared__ char smem[32768];                // [0,16K) A/z/Ebf | [16K,32K) B/E/red
    int t = threadIdx.x, lane = t & 63, w = t >> 6;
    int bid0 = blockIdx.x;                      // 512
    int bid = ((bid0 & 7) << 6) | (bid0 >> 3);  // XCD swizzle
    int posbase = bid << 6;
    int n = posbase >> 10, p0 = (posbase >> 5) & 31;

    int aoff[2];
    #pragma unroll
    for (int i = 0; i < 2; ++i) {
        int r = ((w << 1) + i) * 8 + (lane >> 3);
        int slot = lane & 7;
        int p = p0 + (r >> 5), q = r & 31;
        aoff[i] = (((n * 66 + 2 * p) * 66 + 2 * q) << 7) + ((slot ^ (r & 7)) << 3);
    }
    int boff[4];
    #pragma unroll
    for (int i = 0; i < 4; ++i) {
        int o = ((w << 2) + i) * 8 + (lane >> 3);
        int slot = lane & 7;
        boff[i] = (o << 7) + ((slot ^ (o & 7)) << 3);
    }

    f32x4 acc[4][2];
    #pragma unroll
    for (int mi = 0; mi < 4; ++mi)
        #pragma unroll
        for (int ni = 0; ni < 2; ++ni) acc[mi][ni] = (f32x4){0.f, 0.f, 0.f, 0.f};

    for (int step = 0; step < 32; ++step) {
        int rs = step >> 1, ch = step & 1;
        int aadd = ((((rs >> 2) * 66) + (rs & 3)) << 7) + (ch << 6);
        int badd = (rs << 14) + (ch << 6);
        __syncthreads();
        #pragma unroll
        for (int i = 0; i < 2; ++i)
            gload16(hb + aoff[i] + aadd, &smem[((w << 1) + i) << 10]);
        #pragma unroll
        for (int i = 0; i < 4; ++i)
            gload16(w2p + boff[i] + badd, &smem[16384 + (((w << 2) + i) << 10)]);
        __syncthreads();
        #pragma unroll
        for (int ks = 0; ks < 2; ++ks) {
            bf16x8 av[4], bv[2];
            #pragma unroll
            for (int mi = 0; mi < 4; ++mi)
                av[mi] = *(const bf16x8*)&smem[fragoff64((mi << 4) + (lane & 15), ks, lane)];
            #pragma unroll
            for (int ni = 0; ni < 2; ++ni)
                bv[ni] = *(const bf16x8*)&smem[16384 + fragoff64((w << 5) + (ni << 4) + (lane & 15), ks, lane)];
            #pragma unroll
            for (int mi = 0; mi < 4; ++mi)
                #pragma unroll
                for (int ni = 0; ni < 2; ++ni)
                    acc[mi][ni] = __builtin_amdgcn_mfma_f32_16x16x32_bf16(av[mi], bv[ni], acc[mi][ni], 0, 0, 0);
        }
    }

    // write z (bias + bf16) into LDS A-layout [64 r][128 c], 16-slot swizzle
    __syncthreads();
    {
        int rg = (lane >> 4) << 2;
        #pragma unroll
        for (int mi = 0; mi < 4; ++mi)
            #pragma unroll
            for (int ni = 0; ni < 2; ++ni) {
                int o = (w << 5) + (ni << 4) + (lane & 15);
                float bias = b2[o];
                #pragma unroll
                for (int j = 0; j < 4; ++j) {
                    int r = (mi << 4) + rg + j;
                    int byteoff = (r << 8) + (((((o >> 3) ^ (r & 7))) << 4) | ((o & 7) << 1));
                    __hip_bfloat16 hv = __float2bfloat16(acc[mi][ni][j] + bias);
                    *(__hip_bfloat16*)&smem[byteoff] = hv;
                }
            }
    }
    __syncthreads();

    // VQ: 8 chunks of 64 codes; per wave 16 cols/chunk
    float bvv[4][4];
    int   bii[4][4];
    #pragma unroll
    for (int mi = 0; mi < 4; ++mi)
        #pragma unroll
        for (int j = 0; j < 4; ++j) { bvv[mi][j] = 3.4e38f; bii[mi][j] = 0; }

    for (int chunk = 0; chunk < 8; ++chunk) {
        __syncthreads();
        #pragma unroll
        for (int i = 0; i < 4; ++i) {
            int kl = (((w << 2) + i) << 2) + (lane >> 4);
            int slot = lane & 15;
            gload16(Ep + ((((chunk << 6) + kl) << 7) + ((slot ^ (kl & 7)) << 3)),
                    &smem[16384 + (((w << 2) + i) << 10)]);
        }
        __syncthreads();
        f32x4 a2[4];
        #pragma unroll
        for (int mi = 0; mi < 4; ++mi) a2[mi] = (f32x4){0.f, 0.f, 0.f, 0.f};
        #pragma unroll
        for (int ks = 0; ks < 4; ++ks) {
            bf16x8 av[4], bv;
            #pragma unroll
            for (int mi = 0; mi < 4; ++mi)
                av[mi] = *(const bf16x8*)&smem[fragoff((mi << 4) + (lane & 15), ks, lane)];
            bv = *(const bf16x8*)&smem[16384 + fragoff((w << 4) + (lane & 15), ks, lane)];
            #pragma unroll
            for (int mi = 0; mi < 4; ++mi)
                a2[mi] = __builtin_amdgcn_mfma_f32_16x16x32_bf16(av[mi], bv, a2[mi], 0, 0, 0);
        }
        int kg = (chunk << 6) + (w << 4) + (lane & 15);
        float s2v = s2[kg];
        #pragma unroll
        for (int mi = 0; mi < 4; ++mi)
            #pragma unroll
            for (int j = 0; j < 4; ++j) {
                float sc = s2v - 2.f * a2[mi][j];
                if (sc < bvv[mi][j]) { bvv[mi][j] = sc; bii[mi][j] = kg; }
            }
    }

    __syncthreads();                            // B region reusable now
    float* redv  = (float*)&smem[16384];
    int*   redi  = (int*)&smem[16384 + 1024];
    int*   idx_l = (int*)&smem[16384 + 2048];
    #pragma unroll
    for (int mi = 0; mi < 4; ++mi)
        #pragma unroll
        for (int j = 0; j < 4; ++j) {
            float v = bvv[mi][j];
            int   ix = bii[mi][j];
            #pragma unroll
            for (int m = 1; m < 16; m <<= 1) {
                float ov = __shfl_xor(v, m, 64);
                int   oi = __shfl_xor(ix, m, 64);
                if (ov < v || (ov == v && oi < ix)) { v = ov; ix = oi; }
            }
            if ((lane & 15) == 0) {
                int r = (mi << 4) + ((lane >> 4) << 2) + j;
                redv[(r << 2) + w] = v;
                redi[(r << 2) + w] = ix;
            }
        }
    __syncthreads();
    if (t < 64) {
        float bv_ = redv[t << 2];
        int   bi_ = redi[t << 2];
        #pragma unroll
        for (int w2 = 1; w2 < 4; ++w2) {
            float ov = redv[(t << 2) + w2];
            int   oi = redi[(t << 2) + w2];
            if (ov < bv_ || (ov == bv_ && oi < bi_)) { bv_ = ov; bi_ = oi; }
        }
        idx_l[t] = bi_;
    }
    __syncthreads();

    // stage selected codebook rows (bf16) into [0,16K): [64 r][128 c] linear
    #pragma unroll
    for (int i = 0; i < 4; ++i) {
        int idx2 = (w << 2) + i;
        int r = (idx2 << 2) + (lane >> 4);
        int krow = idx_l[r];
        gload16(Ep + ((krow << 7) + ((lane & 15) << 3)), &smem[idx2 << 10]);
    }
    __syncthreads();

    // scatter: rows posbase..+64 = image n, channels [cd0,cd0+8), all 1024 pos
    int cd0 = (posbase >> 3) & 127;
    const unsigned short* eb = (const unsigned short*)smem;
    #pragma unroll
    for (int k2 = 0; k2 < 4; ++k2) {
        int sp = (k2 << 8) + t;                 // position 0..1023
        int hi = sp >> 7, lo = sp & 127;
        int y = sp >> 5, xx = sp & 31;
        unsigned short vals[8];
        #pragma unroll
        for (int ci = 0; ci < 8; ++ci)
            vals[ci] = eb[(((ci << 3) + hi) << 7) + lo];
        __hip_bfloat16* dst = dq + ((n * 34 + y + 1) * 34 + (xx + 1)) * 128 + cd0;
        *(bf16x8*)dst = *(bf16x8*)vals;
    }
}

// ---- deconv1: dq (padded bf16) -> relu -> g bf16 padded.  BK=64, LDS 32KB ----
__global__ __launch_bounds__(256) void k_deconv1(
    const __hip_bfloat16* __restrict__ dq, const __hip_bfloat16* __restrict__ w1p,
    const float* __restrict__ b1, __hip_bfloat16* __restrict__ g)
{
    __shared__ char smem[32768];                // A 16KB | B 16KB
    int t = threadIdx.x, lane = t & 63, w = t >> 6;
    int wr = w >> 1, wc = w & 1;
    int bid0 = blockIdx.x;                      // 1024
    int bid = ((bid0 & 7) << 7) | (bid0 >> 3);  // XCD swizzle
    int ag = bid & 7, qe = (bid >> 3) & 1, pe = (bid >> 4) & 1, n = bid >> 5;

    int aoff[4], boff[4];
    #pragma unroll
    for (int i = 0; i < 4; ++i) {
        int r = ((w << 2) + i) * 8 + (lane >> 3);
        int slot = lane & 7;
        int a = (ag << 2) + (r >> 5), b = r & 31;
        aoff[i] = (((n * 34 + (a + pe)) * 34 + (b + qe)) << 7) + ((slot ^ (r & 7)) << 3);
        boff[i] = (r << 7) + ((slot ^ (r & 7)) << 3);   // o == r pattern
    }

    f32x4 acc[4][4];
    #pragma unroll
    for (int mi = 0; mi < 4; ++mi)
        #pragma unroll
        for (int ni = 0; ni < 4; ++ni) acc[mi][ni] = (f32x4){0.f, 0.f, 0.f, 0.f};

    int mbase = (pe << 3) | (qe << 2);
    for (int step = 0; step < 8; ++step) {
        int tu = step >> 1, ch = step & 1;
        int tt = tu >> 1, u = tu & 1;
        int aadd = ((tt * 34 + u) << 7) + (ch << 6);
        int badd = ((mbase + tu) << 14) + (ch << 6);
        __syncthreads();
        #pragma unroll
        for (int i = 0; i < 4; ++i) {
            gload16(dq + aoff[i] + aadd, &smem[((w << 2) + i) << 10]);
            gload16(w1p + boff[i] + badd, &smem[16384 + (((w << 2) + i) << 10)]);
        }
        __syncthreads();
        #pragma unroll
        for (int ks = 0; ks < 2; ++ks) {
            bf16x8 av[4], bv[4];
            #pragma unroll
            for (int mi = 0; mi < 4; ++mi)
                av[mi] = *(const bf16x8*)&smem[fragoff64((wr << 6) + (mi << 4) + (lane & 15), ks, lane)];
            #pragma unroll
            for (int ni = 0; ni < 4; ++ni)
                bv[ni] = *(const bf16x8*)&smem[16384 + fragoff64((wc << 6) + (ni << 4) + (lane & 15), ks, lane)];
            #pragma unroll
            for (int mi = 0; mi < 4; ++mi)
                #pragma unroll
                for (int ni = 0; ni < 4; ++ni)
                    acc[mi][ni] = __builtin_amdgcn_mfma_f32_16x16x32_bf16(av[mi], bv[ni], acc[mi][ni], 0, 0, 0);
        }
    }

    int rg = (lane >> 4) << 2;
    #pragma unroll
    for (int mi = 0; mi < 4; ++mi)
        #pragma unroll
        for (int ni = 0; ni < 4; ++ni) {
            int o = (wc << 6) + (ni << 4) + (lane & 15);
            float bias = b1[o];
            #pragma unroll
            for (int j = 0; j < 4; ++j) {
                int row = (wr << 6) + (mi << 4) + rg + j;
                int a = (ag << 2) + (row >> 5), b = row & 31;
                int y = 2 * a + pe, xx2 = 2 * b + qe;
                float v = acc[mi][ni][j] + bias;
                v = v > 0.f ? v : 0.f;
                g[((n * 66 + y + 1) * 66 + xx2 + 1) * 128 + o] = __float2bfloat16(v);
            }
        }
}

// ---- deconv2, 9-neighbor form (unchanged from R5): grid 1024, LDS 36KB ----
__global__ __launch_bounds__(256) void k_deconv2g(
    const __hip_bfloat16* __restrict__ g, const __hip_bfloat16* __restrict__ w2db9,
    const float* __restrict__ b2, float* __restrict__ out)
{
    __shared__ char smem[36864];                // A 32KB | B 4KB
    int t = threadIdx.x, lane = t & 63, w = t >> 6;
    int bid0 = blockIdx.x;                      // 1024
    int bid = ((bid0 & 7) << 7) | (bid0 >> 3);  // XCD swizzle
    int atile = bid & 31, n = bid >> 5;
    int a0 = atile << 1;

    int aoff[8];
    #pragma unroll
    for (int i = 0; i < 8; ++i) {
        int row = (((w << 3) + i) << 2) + (lane >> 4);
        int al = row >> 6, b = row & 63;
        int csw = ((lane & 15) ^ (row & 7)) << 3;
        aoff[i] = (((n * 66 + (a0 + al)) * 66 + b) << 7) + csw;
    }

    f32x4 acc[2];
    acc[0] = (f32x4){0.f, 0.f, 0.f, 0.f};
    acc[1] = (f32x4){0.f, 0.f, 0.f, 0.f};

    for (int de = 0; de < 9; ++de) {
        __syncthreads();
        int dy = de / 3, dx = de - dy * 3;
        int tapoff = ((dy * 66 + dx) << 7);
        #pragma unroll
        for (int i = 0; i < 8; ++i)
            gload16(g + aoff[i] + tapoff, &smem[((w << 3) + i) << 10]);
        gload16(w2db9 + (de << 11) + (w << 9) + (lane << 3), &smem[32768 + (w << 10)]);
        __syncthreads();
        #pragma unroll
        for (int ks = 0; ks < 4; ++ks) {
            bf16x8 av[2], bv;
            #pragma unroll
            for (int mi = 0; mi < 2; ++mi)
                av[mi] = *(const bf16x8*)&smem[fragoff((w << 5) + (mi << 4) + (lane & 15), ks, lane)];
            bv = *(const bf16x8*)&smem[32768 + fragoff(lane & 15, ks, lane)];
            #pragma unroll
            for (int mi = 0; mi < 2; ++mi)
                acc[mi] = __builtin_amdgcn_mfma_f32_16x16x32_bf16(av[mi], bv, acc[mi], 0, 0, 0);
        }
    }

    int rg = (lane >> 4) << 2;
    int col = lane & 15, o = col & 3, pq = col >> 2;
    if (o < 3) {
        int pe = pq >> 1, qe = pq & 1;
        float bias = b2[o];
        #pragma unroll
        for (int mi = 0; mi < 2; ++mi)
            #pragma unroll
            for (int j = 0; j < 4; ++j) {
                int row = (w << 5) + (mi << 4) + rg + j;
                int y = 2 * (a0 + (row >> 6)) + pe;
                int x = 2 * (row & 63) + qe;
                float v = acc[mi][j] + bias;
                out[((n * 3 + o) * 128 + y) * 128 + x] = 1.f / (1.f + expf(-v));
            }
    }
}

extern "C" void kernel_launch(void* const* d_in, const int* in_sizes, int n_in,
                              void* d_out, int out_size, void* d_ws, size_t ws_size,
                              hipStream_t stream) {
    const float* x   = (const float*)d_in[0];
    const float* ew1 = (const float*)d_in[1];
    const float* eb1 = (const float*)d_in[2];
    const float* ew2 = (const float*)d_in[3];
    const float* eb2 = (const float*)d_in[4];
    const float* E   = (const float*)d_in[5];
    const float* dw1 = (const float*)d_in[6];
    const float* db1 = (const float*)d_in[7];
    const float* dw2 = (const float*)d_in[8];
    const float* db2 = (const float*)d_in[9];
    float* out = (float*)d_out;

    char* W = (char*)d_ws;
    __hip_bfloat16* hb    = (__hip_bfloat16*)(W + 0);
    __hip_bfloat16* g     = (__hip_bfloat16*)(W + 0);  // union: hb dead after conv2
    __hip_bfloat16* dq    = (__hip_bfloat16*)(W + 75497472);
    __hip_bfloat16* w2p   = (__hip_bfloat16*)(W + 84967424);
    __hip_bfloat16* w1p   = (__hip_bfloat16*)(W + 85491712);
    __hip_bfloat16* Ep    = (__hip_bfloat16*)(W + 86016000);
    __hip_bfloat16* w2db9 = (__hip_bfloat16*)(W + 86147072);
    float*          s2    = (float*)(W + 86184192);
    __hip_bfloat16* w1b   = (__hip_bfloat16*)(W + 86186240);

    k_init    <<<8682, 256, 0, stream>>>(ew1, ew2, E, dw1, dw2,
                                         hb, w2p, w1p, Ep, w1b, w2db9, dq, s2);
    k_conv1g  <<<1024, 256, 0, stream>>>(x, w1b, eb1, hb);
    k_conv2vq <<<512,  256, 0, stream>>>(hb, w2p, eb2, Ep, s2, dq);
    k_deconv1 <<<1024, 256, 0, stream>>>(dq, w1p, db1, g);
    k_deconv2g<<<1024, 256, 0, stream>>>(g, w2db9, db2, out);
}

// Round 7
// 112.536 us; speedup vs baseline: 22.8873x; 1.0634x over previous
//
#include <hip/hip_runtime.h>
#include <hip/hip_bf16.h>
#include <math.h>

// ---------------------------------------------------------------------------
// VQ-VAE forward. conv1 / conv2+vq / deconv1 / deconv2 are bf16 MFMA implicit
// GEMMs. R7: all K-loops use prefetch double-buffered staging (issue next
// tile's global_load_lds BEFORE computing current tile; ONE barrier per step).
// ws layout (bytes):
//   0          : hb    bf16 [32][66][66][128] (padded conv1 out) 35,684,352
//                g     bf16 [32][66][66][128] (padded deconv1 out, UNION)
//   75497472   : dq    bf16 [32][34][34][128] (padded VQ out)     9,469,952
//   84967424   : w2p   bf16 [16 rs][128 o][128 c] PLAIN             524,288
//   85491712   : w1p   bf16 [16 m ][128 o][128 c] PLAIN             524,288
//   86016000   : Ep    bf16 [512 k][128 c]  PLAIN                   131,072
//   86147072   : w2db9 bf16 [9 de][16 col][128 c] PLAIN              36,864
//   86184192   : s2    f32  [512]                                     2,048
//   86186240   : w1b   bf16 [128 o][64 K] pre-swizzled (conv1)       16,384
// ---------------------------------------------------------------------------

typedef __attribute__((ext_vector_type(8))) short bf16x8;
typedef __attribute__((ext_vector_type(4))) float f32x4;

__device__ __forceinline__ void gload16(const void* g, const void* l) {
    __builtin_amdgcn_global_load_lds(
        (const __attribute__((address_space(1))) void*)g,
        (__attribute__((address_space(3))) void*)l, 16, 0, 0);
}

// byte offset of the 16B fragment (row, ks) in a swizzled [*][128c] bf16 tile (256B rows)
__device__ __forceinline__ int fragoff(int row, int ks, int lane) {
    return (row << 8) + (((ks << 6) + (lane & 0x30)) ^ ((row & 7) << 4));
}
// same for a [*][64c] tile (128B rows), ks in {0,1}
__device__ __forceinline__ int fragoff64(int row, int ks, int lane) {
    return (row << 7) + (((ks << 6) + (lane & 0x30)) ^ ((row & 7) << 4));
}

// ---- k_init: border fills + all weight/codebook prep in one dispatch ----
__global__ __launch_bounds__(256) void k_init(
    const float* __restrict__ ew1, const float* __restrict__ ew2,
    const float* __restrict__ E,   const float* __restrict__ dw1,
    const float* __restrict__ dw2,
    __hip_bfloat16* __restrict__ hb,  __hip_bfloat16* __restrict__ w2p,
    __hip_bfloat16* __restrict__ w1p, __hip_bfloat16* __restrict__ Ep,
    __hip_bfloat16* __restrict__ w1b, __hip_bfloat16* __restrict__ w2db9,
    __hip_bfloat16* __restrict__ dq,  float* __restrict__ s2)
{
    int bid = blockIdx.x, t = threadIdx.x;
    if (bid < 4160) {                               // hb/g border ring
        int tid = bid * 256 + t;                    // 1,064,960
        const int NROW = 32 * 2 * 66 * 128;
        if (tid < NROW) {
            int c = tid & 127;
            int xx = (tid >> 7) % 66;
            int r2 = tid / (66 * 128);
            int yy = (r2 & 1) * 65;
            int n = r2 >> 1;
            hb[((n * 66 + yy) * 66 + xx) * 128 + c] = __float2bfloat16(0.f);
        } else {
            int t2 = tid - NROW;
            int c = t2 & 127;
            int xs = (t2 >> 7) & 1;
            int yy = ((t2 >> 8) & 63) + 1;
            int n = t2 >> 14;
            hb[((n * 66 + yy) * 66 + xs * 65) * 128 + c] = __float2bfloat16(0.f);
        }
    } else if (bid < 5184) {                        // w2p plain [rs][o][c]
        int tid = (bid - 4160) * 256 + t;           // 262144
        int c = tid & 127, o = (tid >> 7) & 127, rs = tid >> 14;
        int r = rs >> 2, s = rs & 3;
        w2p[tid] = __float2bfloat16(ew2[((o * 128 + c) * 4 + r) * 4 + s]);
    } else if (bid < 6208) {                        // w1p plain [m][o][c]
        int tid = (bid - 5184) * 256 + t;           // 262144
        int c = tid & 127, o = (tid >> 7) & 127, m = tid >> 14;
        int pe = (m >> 3) & 1, qe = (m >> 2) & 1, tt = (m >> 1) & 1, u = m & 1;
        w1p[tid] = __float2bfloat16(dw1[((o * 128 + c) * 4 + (pe + 2 * tt)) * 4 + (qe + 2 * u)]);
    } else if (bid < 6464) {                        // Ep plain [k][c]
        int tid = (bid - 6208) * 256 + t;           // 65536
        Ep[tid] = __float2bfloat16(E[tid]);
    } else if (bid < 6496) {                        // w1b (conv1, pre-swizzled, K pad 48->64)
        int tid = (bid - 6464) * 256 + t;           // 8192
        int o = tid >> 6, cpos = tid & 63;
        int slot = cpos >> 3, e = cpos & 7;
        int k = ((slot ^ (o & 7)) << 3) | e;
        float v = 0.f;
        if (k < 48) {
            int c = k >> 4, r = (k >> 2) & 3, s = k & 3;
            v = ew1[((o * 3 + c) * 4 + r) * 4 + s];
        }
        w1b[tid] = __float2bfloat16(v);
    } else if (bid < 6568) {                        // w2db9 plain [9 de][16 col][128 c]
        int tid = (bid - 6496) * 256 + t;           // 18432
        int c = tid & 127;
        int col = (tid >> 7) & 15;
        int de = tid >> 11;                         // 0..8
        int o = col & 3, pq = col >> 2;
        int d = de / 3, e_ = de - d * 3;
        int pe = pq >> 1, qe = pq & 1;
        int tt = d - pe, u = e_ - qe;
        float v = 0.f;
        if (o < 3 && tt >= 0 && tt < 2 && u >= 0 && u < 2)
            v = dw2[((o * 128 + c) * 4 + (pe + 2 * tt)) * 4 + (qe + 2 * u)];
        w2db9[tid] = __float2bfloat16(v);
    } else if (bid < 6570) {                        // sumE2
        int k = (bid - 6568) * 256 + t;             // 512
        float a = 0.f;
        const float* e = E + k * 128;
        for (int c = 0; c < 128; ++c) a = fmaf(e[c], e[c], a);
        s2[k] = a;
    } else {                                        // dq border ring
        int tid = (bid - 6570) * 256 + t;           // 540,672  (2112 blocks)
        int n = tid / 16896;
        int rem = tid - n * 16896;
        int c = rem & 127;
        int pp = rem >> 7;                          // 0..131
        int yy, xx;
        if (pp < 68) { yy = (pp >= 34) ? 33 : 0; xx = pp % 34; }
        else { int q = pp - 68; yy = 1 + (q >> 1); xx = (q & 1) * 33; }
        dq[((n * 34 + yy) * 34 + xx) * 128 + c] = __float2bfloat16(0.f);
    }
}

// ---- conv1 as MFMA implicit GEMM; x-window staged to LDS via 9 gload16 ----
__global__ __launch_bounds__(256) void k_conv1g(
    const float* __restrict__ x, const __hip_bfloat16* __restrict__ w1b,
    const float* __restrict__ b1, __hip_bfloat16* __restrict__ hb)
{
    __shared__ char smem[41984];                    // A 16K | B 16K | xw 9216
    int t = threadIdx.x, lane = t & 63, w = t >> 6;
    int wr = w >> 1, wc = w & 1;
    int bid0 = blockIdx.x;                          // 1024
    int bid = ((bid0 & 7) << 7) | (bid0 >> 3);      // XCD swizzle
    int posbase = bid << 7;
    int ng = posbase >> 12, p0g = (posbase >> 6) & 63;

    // B staging
    #pragma unroll
    for (int i = 0; i < 4; ++i)
        gload16(w1b + ((w * 4 + i) * 512 + lane * 8), &smem[16384 + ((w * 4 + i) << 10)]);

    // x-window staging: xw f32 [18 wrow = c*6+yy][128], rows y = 2*p0g-1+yy (clamped)
    #pragma unroll
    for (int k3 = 0; k3 < 3; ++k3) {
        int j = w + (k3 << 2);
        if (j < 9) {
            int wrow = (j << 1) | (lane >> 5);
            int c = wrow / 6, yy = wrow - c * 6;
            int y = 2 * p0g - 1 + yy;
            int ysrc = y < 0 ? 0 : (y > 127 ? 127 : y);
            gload16(x + (((ng * 3 + c) * 128 + ysrc) << 7) + ((lane & 31) << 2),
                    &smem[32768 + (j << 10)]);
        }
    }
    __syncthreads();

    // im2col pack from LDS window (validity masked here)
    {
        int row = t >> 1, half = t & 1;
        int pl = row >> 6, q = row & 63;
        #pragma unroll
        for (int j = 0; j < 4; ++j) {
            int d = half * 4 + j;
            int sct = d ^ (row & 7);
            __hip_bfloat16 hv[8];
            #pragma unroll
            for (int e = 0; e < 8; ++e) {
                int k = sct * 8 + e;
                float v = 0.f;
                if (k < 48) {
                    int c = k >> 4, r = (k >> 2) & 3, s4 = k & 3;
                    int y = 2 * (p0g + pl) + r - 1;
                    int xg = 2 * q + s4 - 1;
                    if (((unsigned)y < 128u) && ((unsigned)xg < 128u)) {
                        int wrow = c * 6 + 2 * pl + r;
                        v = *(const float*)&smem[32768 + (wrow << 9) + (xg << 2)];
                    }
                }
                hv[e] = __float2bfloat16(v);
            }
            *(bf16x8*)&smem[(row << 7) + d * 16] = *(bf16x8*)hv;
        }
    }
    __syncthreads();

    f32x4 acc[4][4];
    #pragma unroll
    for (int mi = 0; mi < 4; ++mi)
        #pragma unroll
        for (int ni = 0; ni < 4; ++ni) acc[mi][ni] = (f32x4){0.f, 0.f, 0.f, 0.f};

    #pragma unroll
    for (int ks = 0; ks < 2; ++ks) {
        bf16x8 av[4], bv[4];
        #pragma unroll
        for (int mi = 0; mi < 4; ++mi)
            av[mi] = *(const bf16x8*)&smem[fragoff64((wr << 6) + (mi << 4) + (lane & 15), ks, lane)];
        #pragma unroll
        for (int ni = 0; ni < 4; ++ni)
            bv[ni] = *(const bf16x8*)&smem[16384 + fragoff64((wc << 6) + (ni << 4) + (lane & 15), ks, lane)];
        #pragma unroll
        for (int mi = 0; mi < 4; ++mi)
            #pragma unroll
            for (int ni = 0; ni < 4; ++ni)
                acc[mi][ni] = __builtin_amdgcn_mfma_f32_16x16x32_bf16(av[mi], bv[ni], acc[mi][ni], 0, 0, 0);
    }

    int rg = (lane >> 4) << 2;
    #pragma unroll
    for (int mi = 0; mi < 4; ++mi)
        #pragma unroll
        for (int ni = 0; ni < 4; ++ni) {
            int o = (wc << 6) + (ni << 4) + (lane & 15);
            float bias = b1[o];
            #pragma unroll
            for (int j = 0; j < 4; ++j) {
                int rowg = posbase + (wr << 6) + (mi << 4) + rg + j;
                int n = rowg >> 12, p = (rowg >> 6) & 63, q = rowg & 63;
                float v = acc[mi][ni][j] + bias;
                v = v > 0.f ? v : 0.f;
                hb[((n * 66 + p + 1) * 66 + q + 1) * 128 + o] = __float2bfloat16(v);
            }
        }
}

// ---- conv2 + VQ fused, prefetch-dbuf.  M=64, BK=64, 32 steps, 1 barrier/step ----
__global__ __launch_bounds__(256) void k_conv2vq(
    const __hip_bfloat16* __restrict__ hb, const __hip_bfloat16* __restrict__ w2p,
    const float* __restrict__ b2, const __hip_bfloat16* __restrict__ Ep,
    const float* __restrict__ s2, __hip_bfloat16* __restrict__ dq)
{
    __shared__ char smem[49152];                // buf b at b*24576: A 8K | B 16K
    int t = threadIdx.x, lane = t & 63, w = t >> 6;
    int bid0 = blockIdx.x;                      // 512
    int bid = ((bid0 & 7) << 6) | (bid0 >> 3);  // XCD swizzle
    int posbase = bid << 6;
    int n = posbase >> 10, p0 = (posbase >> 5) & 31;

    int aoff[2];
    #pragma unroll
    for (int i = 0; i < 2; ++i) {
        int r = ((w << 1) + i) * 8 + (lane >> 3);
        int slot = lane & 7;
        int p = p0 + (r >> 5), q = r & 31;
        aoff[i] = (((n * 66 + 2 * p) * 66 + 2 * q) << 7) + ((slot ^ (r & 7)) << 3);
    }
    int boff[4];
    #pragma unroll
    for (int i = 0; i < 4; ++i) {
        int o = ((w << 2) + i) * 8 + (lane >> 3);
        int slot = lane & 7;
        boff[i] = (o << 7) + ((slot ^ (o & 7)) << 3);
    }

#define C2_STAGE(STEP, BASE) { \
    int rs_ = (STEP) >> 1, ch_ = (STEP) & 1; \
    int aadd_ = ((((rs_ >> 2) * 66) + (rs_ & 3)) << 7) + (ch_ << 6); \
    int badd_ = (rs_ << 14) + (ch_ << 6); \
    _Pragma("unroll") \
    for (int i = 0; i < 2; ++i) \
        gload16(hb + aoff[i] + aadd_, &smem[(BASE) + (((w << 1) + i) << 10)]); \
    _Pragma("unroll") \
    for (int i = 0; i < 4; ++i) \
        gload16(w2p + boff[i] + badd_, &smem[(BASE) + 8192 + (((w << 2) + i) << 10)]); }

    f32x4 acc[4][2];
    #pragma unroll
    for (int mi = 0; mi < 4; ++mi)
        #pragma unroll
        for (int ni = 0; ni < 2; ++ni) acc[mi][ni] = (f32x4){0.f, 0.f, 0.f, 0.f};

    C2_STAGE(0, 0);
    __syncthreads();
    for (int step = 0; step < 32; ++step) {
        int cb = (step & 1) * 24576;
        if (step < 31) C2_STAGE(step + 1, ((step + 1) & 1) * 24576);
        #pragma unroll
        for (int ks = 0; ks < 2; ++ks) {
            bf16x8 av[4], bv[2];
            #pragma unroll
            for (int mi = 0; mi < 4; ++mi)
                av[mi] = *(const bf16x8*)&smem[cb + fragoff64((mi << 4) + (lane & 15), ks, lane)];
            #pragma unroll
            for (int ni = 0; ni < 2; ++ni)
                bv[ni] = *(const bf16x8*)&smem[cb + 8192 + fragoff64((w << 5) + (ni << 4) + (lane & 15), ks, lane)];
            #pragma unroll
            for (int mi = 0; mi < 4; ++mi)
                #pragma unroll
                for (int ni = 0; ni < 2; ++ni)
                    acc[mi][ni] = __builtin_amdgcn_mfma_f32_16x16x32_bf16(av[mi], bv[ni], acc[mi][ni], 0, 0, 0);
        }
        __syncthreads();
    }

#define VQ_STAGE(CHUNK, BASE) { \
    _Pragma("unroll") \
    for (int i = 0; i < 4; ++i) { \
        int kl_ = (((w << 2) + i) << 2) + (lane >> 4); \
        gload16(Ep + ((((CHUNK) << 6) + kl_) << 7) + (((lane & 15) ^ (kl_ & 7)) << 3), \
                &smem[(BASE) + (((w << 2) + i) << 10)]); \
    } }

    // write z (bias + bf16) into LDS A-layout [64 r][128 c] at [0,16K), and
    // prefetch E chunk 0 — one barrier covers both.
    {
        int rg = (lane >> 4) << 2;
        #pragma unroll
        for (int mi = 0; mi < 4; ++mi)
            #pragma unroll
            for (int ni = 0; ni < 2; ++ni) {
                int o = (w << 5) + (ni << 4) + (lane & 15);
                float bias = b2[o];
                #pragma unroll
                for (int j = 0; j < 4; ++j) {
                    int r = (mi << 4) + rg + j;
                    int byteoff = (r << 8) + (((((o >> 3) ^ (r & 7))) << 4) | ((o & 7) << 1));
                    __hip_bfloat16 hv = __float2bfloat16(acc[mi][ni][j] + bias);
                    *(__hip_bfloat16*)&smem[byteoff] = hv;
                }
            }
    }
    VQ_STAGE(0, 16384);
    __syncthreads();

    float bvv[4][4];
    int   bii[4][4];
    #pragma unroll
    for (int mi = 0; mi < 4; ++mi)
        #pragma unroll
        for (int j = 0; j < 4; ++j) { bvv[mi][j] = 3.4e38f; bii[mi][j] = 0; }

    for (int chunk = 0; chunk < 8; ++chunk) {
        int eb = 16384 + ((chunk & 1) << 14);
        if (chunk < 7) VQ_STAGE(chunk + 1, 16384 + (((chunk + 1) & 1) << 14));
        f32x4 a2[4];
        #pragma unroll
        for (int mi = 0; mi < 4; ++mi) a2[mi] = (f32x4){0.f, 0.f, 0.f, 0.f};
        #pragma unroll
        for (int ks = 0; ks < 4; ++ks) {
            bf16x8 av[4], bv;
            #pragma unroll
            for (int mi = 0; mi < 4; ++mi)
                av[mi] = *(const bf16x8*)&smem[fragoff((mi << 4) + (lane & 15), ks, lane)];
            bv = *(const bf16x8*)&smem[eb + fragoff((w << 4) + (lane & 15), ks, lane)];
            #pragma unroll
            for (int mi = 0; mi < 4; ++mi)
                a2[mi] = __builtin_amdgcn_mfma_f32_16x16x32_bf16(av[mi], bv, a2[mi], 0, 0, 0);
        }
        int kg = (chunk << 6) + (w << 4) + (lane & 15);
        float s2v = s2[kg];
        #pragma unroll
        for (int mi = 0; mi < 4; ++mi)
            #pragma unroll
            for (int j = 0; j < 4; ++j) {
                float sc = s2v - 2.f * a2[mi][j];
                if (sc < bvv[mi][j]) { bvv[mi][j] = sc; bii[mi][j] = kg; }
            }
        __syncthreads();
    }

    float* redv  = (float*)&smem[16384];
    int*   redi  = (int*)&smem[16384 + 1024];
    int*   idx_l = (int*)&smem[16384 + 2048];
    #pragma unroll
    for (int mi = 0; mi < 4; ++mi)
        #pragma unroll
        for (int j = 0; j < 4; ++j) {
            float v = bvv[mi][j];
            int   ix = bii[mi][j];
            #pragma unroll
            for (int m = 1; m < 16; m <<= 1) {
                float ov = __shfl_xor(v, m, 64);
                int   oi = __shfl_xor(ix, m, 64);
                if (ov < v || (ov == v && oi < ix)) { v = ov; ix = oi; }
            }
            if ((lane & 15) == 0) {
                int r = (mi << 4) + ((lane >> 4) << 2) + j;
                redv[(r << 2) + w] = v;
                redi[(r << 2) + w] = ix;
            }
        }
    __syncthreads();
    if (t < 64) {
        float bv_ = redv[t << 2];
        int   bi_ = redi[t << 2];
        #pragma unroll
        for (int w2 = 1; w2 < 4; ++w2) {
            float ov = redv[(t << 2) + w2];
            int   oi = redi[(t << 2) + w2];
            if (ov < bv_ || (ov == bv_ && oi < bi_)) { bv_ = ov; bi_ = oi; }
        }
        idx_l[t] = bi_;
    }
    __syncthreads();

    // stage selected codebook rows (bf16) into [0,16K): [64 r][128 c] linear
    #pragma unroll
    for (int i = 0; i < 4; ++i) {
        int idx2 = (w << 2) + i;
        int r = (idx2 << 2) + (lane >> 4);
        int krow = idx_l[r];
        gload16(Ep + ((krow << 7) + ((lane & 15) << 3)), &smem[idx2 << 10]);
    }
    __syncthreads();

    // scatter: rows posbase..+64 = image n, channels [cd0,cd0+8), all 1024 pos
    int cd0 = (posbase >> 3) & 127;
    const unsigned short* eb2p = (const unsigned short*)smem;
    #pragma unroll
    for (int k2 = 0; k2 < 4; ++k2) {
        int sp = (k2 << 8) + t;
        int hi = sp >> 7, lo = sp & 127;
        int y = sp >> 5, xx = sp & 31;
        unsigned short vals[8];
        #pragma unroll
        for (int ci = 0; ci < 8; ++ci)
            vals[ci] = eb2p[(((ci << 3) + hi) << 7) + lo];
        __hip_bfloat16* dst = dq + ((n * 34 + y + 1) * 34 + (xx + 1)) * 128 + cd0;
        *(bf16x8*)dst = *(bf16x8*)vals;
    }
}

// ---- deconv1, prefetch-dbuf: M=128, BK=64, 8 steps, 1 barrier/step ----
__global__ __launch_bounds__(256) void k_deconv1(
    const __hip_bfloat16* __restrict__ dq, const __hip_bfloat16* __restrict__ w1p,
    const float* __restrict__ b1, __hip_bfloat16* __restrict__ g)
{
    __shared__ char smem[65536];                // buf b at b*32768: A 16K | B 16K
    int t = threadIdx.x, lane = t & 63, w = t >> 6;
    int wr = w >> 1, wc = w & 1;
    int bid0 = blockIdx.x;                      // 1024
    int bid = ((bid0 & 7) << 7) | (bid0 >> 3);  // XCD swizzle
    int ag = bid & 7, qe = (bid >> 3) & 1, pe = (bid >> 4) & 1, n = bid >> 5;

    int aoff[4], boff[4];
    #pragma unroll
    for (int i = 0; i < 4; ++i) {
        int r = ((w << 2) + i) * 8 + (lane >> 3);
        int slot = lane & 7;
        int a = (ag << 2) + (r >> 5), b = r & 31;
        aoff[i] = (((n * 34 + (a + pe)) * 34 + (b + qe)) << 7) + ((slot ^ (r & 7)) << 3);
        boff[i] = (r << 7) + ((slot ^ (r & 7)) << 3);
    }
    int mbase = (pe << 3) | (qe << 2);

#define D1_STAGE(STEP, BASE) { \
    int tu_ = (STEP) >> 1, ch_ = (STEP) & 1; \
    int tt_ = tu_ >> 1, u_ = tu_ & 1; \
    int aadd_ = ((tt_ * 34 + u_) << 7) + (ch_ << 6); \
    int badd_ = ((mbase + tu_) << 14) + (ch_ << 6); \
    _Pragma("unroll") \
    for (int i = 0; i < 4; ++i) { \
        gload16(dq + aoff[i] + aadd_, &smem[(BASE) + (((w << 2) + i) << 10)]); \
        gload16(w1p + boff[i] + badd_, &smem[(BASE) + 16384 + (((w << 2) + i) << 10)]); \
    } }

    f32x4 acc[4][4];
    #pragma unroll
    for (int mi = 0; mi < 4; ++mi)
        #pragma unroll
        for (int ni = 0; ni < 4; ++ni) acc[mi][ni] = (f32x4){0.f, 0.f, 0.f, 0.f};

    D1_STAGE(0, 0);
    __syncthreads();
    for (int step = 0; step < 8; ++step) {
        int cb = (step & 1) * 32768;
        if (step < 7) D1_STAGE(step + 1, ((step + 1) & 1) * 32768);
        #pragma unroll
        for (int ks = 0; ks < 2; ++ks) {
            bf16x8 av[4], bv[4];
            #pragma unroll
            for (int mi = 0; mi < 4; ++mi)
                av[mi] = *(const bf16x8*)&smem[cb + fragoff64((wr << 6) + (mi << 4) + (lane & 15), ks, lane)];
            #pragma unroll
            for (int ni = 0; ni < 4; ++ni)
                bv[ni] = *(const bf16x8*)&smem[cb + 16384 + fragoff64((wc << 6) + (ni << 4) + (lane & 15), ks, lane)];
            #pragma unroll
            for (int mi = 0; mi < 4; ++mi)
                #pragma unroll
                for (int ni = 0; ni < 4; ++ni)
                    acc[mi][ni] = __builtin_amdgcn_mfma_f32_16x16x32_bf16(av[mi], bv[ni], acc[mi][ni], 0, 0, 0);
        }
        __syncthreads();
    }

    int rg = (lane >> 4) << 2;
    #pragma unroll
    for (int mi = 0; mi < 4; ++mi)
        #pragma unroll
        for (int ni = 0; ni < 4; ++ni) {
            int o = (wc << 6) + (ni << 4) + (lane & 15);
            float bias = b1[o];
            #pragma unroll
            for (int j = 0; j < 4; ++j) {
                int row = (wr << 6) + (mi << 4) + rg + j;
                int a = (ag << 2) + (row >> 5), b = row & 31;
                int y = 2 * a + pe, xx2 = 2 * b + qe;
                float v = acc[mi][ni][j] + bias;
                v = v > 0.f ? v : 0.f;
                g[((n * 66 + y + 1) * 66 + xx2 + 1) * 128 + o] = __float2bfloat16(v);
            }
        }
}

// ---- deconv2, 9-neighbor, prefetch-dbuf: BK=64, 18 steps, 1 barrier/step ----
__global__ __launch_bounds__(256) void k_deconv2g(
    const __hip_bfloat16* __restrict__ g, const __hip_bfloat16* __restrict__ w2db9,
    const float* __restrict__ b2, float* __restrict__ out)
{
    __shared__ char smem[36864];                // buf b at b*18432: A 16K | B 2K
    int t = threadIdx.x, lane = t & 63, w = t >> 6;
    int bid0 = blockIdx.x;                      // 1024
    int bid = ((bid0 & 7) << 7) | (bid0 >> 3);  // XCD swizzle
    int atile = bid & 31, n = bid >> 5;
    int a0 = atile << 1;

    int aoff[4];
    #pragma unroll
    for (int i = 0; i < 4; ++i) {
        int r = ((w << 2) + i) * 8 + (lane >> 3);
        int al = r >> 6, b = r & 63;
        aoff[i] = (((n * 66 + (a0 + al)) * 66 + b) << 7) + (((lane & 7) ^ (r & 7)) << 3);
    }

#define D2_STAGE(STEP, BASE) { \
    int de_ = (STEP) >> 1, ch_ = (STEP) & 1; \
    int dy_ = de_ / 3, dx_ = de_ - dy_ * 3; \
    int aadd_ = ((dy_ * 66 + dx_) << 7) + (ch_ << 6); \
    _Pragma("unroll") \
    for (int i = 0; i < 4; ++i) \
        gload16(g + aoff[i] + aadd_, &smem[(BASE) + (((w << 2) + i) << 10)]); \
    if (w < 2) { \
        int kl_ = (w << 3) + (lane >> 3); \
        gload16(w2db9 + (de_ << 11) + (kl_ << 7) + (ch_ << 6) + (((lane & 7) ^ (kl_ & 7)) << 3), \
                &smem[(BASE) + 16384 + (w << 10)]); \
    } }

    f32x4 acc[2];
    acc[0] = (f32x4){0.f, 0.f, 0.f, 0.f};
    acc[1] = (f32x4){0.f, 0.f, 0.f, 0.f};

    D2_STAGE(0, 0);
    __syncthreads();
    for (int step = 0; step < 18; ++step) {
        int cb = (step & 1) * 18432;
        if (step < 17) D2_STAGE(step + 1, ((step + 1) & 1) * 18432);
        #pragma unroll
        for (int ks = 0; ks < 2; ++ks) {
            bf16x8 av[2], bv;
            #pragma unroll
            for (int mi = 0; mi < 2; ++mi)
                av[mi] = *(const bf16x8*)&smem[cb + fragoff64((w << 5) + (mi << 4) + (lane & 15), ks, lane)];
            bv = *(const bf16x8*)&smem[cb + 16384 + fragoff64(lane & 15, ks, lane)];
            #pragma unroll
            for (int mi = 0; mi < 2; ++mi)
                acc[mi] = __builtin_amdgcn_mfma_f32_16x16x32_bf16(av[mi], bv, acc[mi], 0, 0, 0);
        }
        __syncthreads();
    }

    int rg = (lane >> 4) << 2;
    int col = lane & 15, o = col & 3, pq = col >> 2;
    if (o < 3) {
        int pe = pq >> 1, qe = pq & 1;
        float bias = b2[o];
        #pragma unroll
        for (int mi = 0; mi < 2; ++mi)
            #pragma unroll
            for (int j = 0; j < 4; ++j) {
                int row = (w << 5) + (mi << 4) + rg + j;
                int y = 2 * (a0 + (row >> 6)) + pe;
                int x = 2 * (row & 63) + qe;
                float v = acc[mi][j] + bias;
                out[((n * 3 + o) * 128 + y) * 128 + x] = 1.f / (1.f + expf(-v));
            }
    }
}

extern "C" void kernel_launch(void* const* d_in, const int* in_sizes, int n_in,
                              void* d_out, int out_size, void* d_ws, size_t ws_size,
                              hipStream_t stream) {
    const float* x   = (const float*)d_in[0];
    const float* ew1 = (const float*)d_in[1];
    const float* eb1 = (const float*)d_in[2];
    const float* ew2 = (const float*)d_in[3];
    const float* eb2 = (const float*)d_in[4];
    const float* E   = (const float*)d_in[5];
    const float* dw1 = (const float*)d_in[6];
    const float* db1 = (const float*)d_in[7];
    const float* dw2 = (const float*)d_in[8];
    const float* db2 = (const float*)d_in[9];
    float* out = (float*)d_out;

    char* W = (char*)d_ws;
    __hip_bfloat16* hb    = (__hip_bfloat16*)(W + 0);
    __hip_bfloat16* g     = (__hip_bfloat16*)(W + 0);  // union: hb dead after conv2
    __hip_bfloat16* dq    = (__hip_bfloat16*)(W + 75497472);
    __hip_bfloat16* w2p   = (__hip_bfloat16*)(W + 84967424);
    __hip_bfloat16* w1p   = (__hip_bfloat16*)(W + 85491712);
    __hip_bfloat16* Ep    = (__hip_bfloat16*)(W + 86016000);
    __hip_bfloat16* w2db9 = (__hip_bfloat16*)(W + 86147072);
    float*          s2    = (float*)(W + 86184192);
    __hip_bfloat16* w1b   = (__hip_bfloat16*)(W + 86186240);

    k_init    <<<8682, 256, 0, stream>>>(ew1, ew2, E, dw1, dw2,
                                         hb, w2p, w1p, Ep, w1b, w2db9, dq, s2);
    k_conv1g  <<<1024, 256, 0, stream>>>(x, w1b, eb1, hb);
    k_conv2vq <<<512,  256, 0, stream>>>(hb, w2p, eb2, Ep, s2, dq);
    k_deconv1 <<<1024, 256, 0, stream>>>(dq, w1p, db1, g);
    k_deconv2g<<<1024, 256, 0, stream>>>(g, w2db9, db2, out);
}